// Round 1
// baseline (683.194 us; speedup 1.0000x reference)
//
#include <hip/hip_runtime.h>
#include <hip/hip_bf16.h>

// ---------------------------------------------------------------------------
// GCN encoder: 2x { h = x@W ; out[dst] += norm*h[src] (incl self-loop) ; +b ; relu? }
// norm = dinv[src]*dinv[dst], dinv = rsqrt(1 + indegree)
// Strategy: build CSR-by-dst once (histogram + scan + atomic scatter), then
// per layer: fp32 GEMM (LDS-staged W + x-tile, 4x4 reg tile) followed by a
// wave-per-node gather-accumulate (no float atomics), bias/ReLU fused.
// ---------------------------------------------------------------------------

__global__ __launch_bounds__(256) void count_kernel(
    const int* __restrict__ dst, int* __restrict__ cnt, int E)
{
    int e = blockIdx.x * 256 + threadIdx.x;
    if (e < E) atomicAdd(&cnt[dst[e]], 1);
}

__global__ __launch_bounds__(256) void dinv_kernel(
    const int* __restrict__ cnt, float* __restrict__ dinv, int n)
{
    int i = blockIdx.x * 256 + threadIdx.x;
    if (i < n) dinv[i] = rsqrtf((float)(cnt[i] + 1));   // +1: self loop
}

// single-block exclusive scan of cnt[0..n) -> rowptr[0..n], cursor copy
__global__ __launch_bounds__(1024) void scan_kernel(
    const int* __restrict__ cnt, int* __restrict__ rowptr,
    int* __restrict__ cursor, int n)
{
    __shared__ int wsum[16];
    int t = threadIdx.x;
    int lane = t & 63, wv = t >> 6;
    int base = 0;
    for (int start = 0; start < n; start += 1024) {
        int i = start + t;
        int v = (i < n) ? cnt[i] : 0;
        int x = v;
        #pragma unroll
        for (int d = 1; d < 64; d <<= 1) {
            int y = __shfl_up(x, d);
            if (lane >= d) x += y;
        }
        if (lane == 63) wsum[wv] = x;
        __syncthreads();
        if (wv == 0 && lane < 16) {
            int s = wsum[lane];
            #pragma unroll
            for (int d = 1; d < 16; d <<= 1) {
                int y = __shfl_up(s, d);
                if (lane >= d) s += y;
            }
            wsum[lane] = s;
        }
        __syncthreads();
        int wbase = (wv == 0) ? 0 : wsum[wv - 1];
        int excl = base + wbase + (x - v);
        if (i < n) { rowptr[i] = excl; cursor[i] = excl; }
        base += wsum[15];
        __syncthreads();
    }
    if (t == 0) rowptr[n] = base;
}

__global__ __launch_bounds__(256) void scatter_kernel(
    const int* __restrict__ src, const int* __restrict__ dst,
    int* __restrict__ cursor, int* __restrict__ csrsrc, int E)
{
    int e = blockIdx.x * 256 + threadIdx.x;
    if (e < E) {
        int d = dst[e];
        int pos = atomicAdd(&cursor[d], 1);
        csrsrc[pos] = src[e];
    }
}

// out[M x 128] = A[M x 128] @ W[128 x 128], fp32.
// Block: 256 threads, 32 rows per block. W + transposed x-tile in LDS.
__global__ __launch_bounds__(256) void gemm128_kernel(
    const float* __restrict__ A, const float* __restrict__ W,
    float* __restrict__ out, int M)
{
    __shared__ float Wl[128 * 128];
    __shared__ float Xt[128][32];            // Xt[k][r]
    const float4* W4 = (const float4*)W;
    float4* Wl4 = (float4*)Wl;
    #pragma unroll
    for (int j = 0; j < 16; ++j)
        Wl4[threadIdx.x + j * 256] = W4[threadIdx.x + j * 256];

    int row0 = blockIdx.x * 32;
    const float4* A4 = (const float4*)(A + (size_t)row0 * 128);
    #pragma unroll
    for (int j = 0; j < 4; ++j) {
        int i = threadIdx.x + j * 256;       // float4 index in 32x128 tile
        int r = i >> 5, c4 = i & 31;
        float4 v = A4[(size_t)r * 32 + c4];
        Xt[c4 * 4 + 0][r] = v.x; Xt[c4 * 4 + 1][r] = v.y;
        Xt[c4 * 4 + 2][r] = v.z; Xt[c4 * 4 + 3][r] = v.w;
    }
    __syncthreads();

    int cg = threadIdx.x & 31;               // 4 cols: 4*cg..
    int rg = threadIdx.x >> 5;               // 4 rows: 4*rg..
    float acc[4][4] = {};
    #pragma unroll 8
    for (int k = 0; k < 128; ++k) {
        float4 xv = *(const float4*)&Xt[k][rg * 4];
        float4 wv = *(const float4*)&Wl[k * 128 + cg * 4];
        acc[0][0] += xv.x * wv.x; acc[0][1] += xv.x * wv.y;
        acc[0][2] += xv.x * wv.z; acc[0][3] += xv.x * wv.w;
        acc[1][0] += xv.y * wv.x; acc[1][1] += xv.y * wv.y;
        acc[1][2] += xv.y * wv.z; acc[1][3] += xv.y * wv.w;
        acc[2][0] += xv.z * wv.x; acc[2][1] += xv.z * wv.y;
        acc[2][2] += xv.z * wv.z; acc[2][3] += xv.z * wv.w;
        acc[3][0] += xv.w * wv.x; acc[3][1] += xv.w * wv.y;
        acc[3][2] += xv.w * wv.z; acc[3][3] += xv.w * wv.w;
    }
    #pragma unroll
    for (int i2 = 0; i2 < 4; ++i2) {
        int row = row0 + rg * 4 + i2;
        if (row < M) {
            float4 o = make_float4(acc[i2][0], acc[i2][1], acc[i2][2], acc[i2][3]);
            *(float4*)&out[(size_t)row * 128 + cg * 4] = o;
        }
    }
}

// one wave per node: acc[128] (float2/lane) = sum over incoming edges of
// dinv[dst]*dinv[src]*h[src] + dinv[dst]^2*h[dst], + bias, opt ReLU.
template <bool RELU>
__global__ __launch_bounds__(256) void agg_kernel(
    const float* __restrict__ h, const float* __restrict__ dinv,
    const int* __restrict__ rowptr, const int* __restrict__ csrsrc,
    const float* __restrict__ bias, float* __restrict__ out, int n)
{
    int wid = blockIdx.x * 4 + (threadIdx.x >> 6);
    if (wid >= n) return;
    int lane = threadIdx.x & 63;
    const float2* hv = (const float2*)h;

    float di = dinv[wid];
    int beg = rowptr[wid], end = rowptr[wid + 1];

    // self loop
    float2 vs = hv[(size_t)wid * 64 + lane];
    float w0 = di * di;
    float accx = vs.x * w0, accy = vs.y * w0;

    for (int eb = beg; eb < end; eb += 64) {
        int idx = eb + lane;
        int sl = (idx < end) ? csrsrc[idx] : 0;
        float dl = (idx < end) ? dinv[sl] : 0.0f;
        int m = end - eb; if (m > 64) m = 64;
        for (int j = 0; j < m; ++j) {
            int s = __shfl(sl, j);
            float w = di * __shfl(dl, j);
            float2 v = hv[(size_t)s * 64 + lane];
            accx += v.x * w; accy += v.y * w;
        }
    }
    float2 b = ((const float2*)bias)[lane];
    accx += b.x; accy += b.y;
    if (RELU) { accx = fmaxf(accx, 0.0f); accy = fmaxf(accy, 0.0f); }
    float2 o; o.x = accx; o.y = accy;
    ((float2*)out)[(size_t)wid * 64 + lane] = o;
}

extern "C" void kernel_launch(void* const* d_in, const int* in_sizes, int n_in,
                              void* d_out, int out_size, void* d_ws, size_t ws_size,
                              hipStream_t stream)
{
    const float* x  = (const float*)d_in[0];
    const int*   ei = (const int*)d_in[1];
    const float* W1 = (const float*)d_in[2];
    const float* b1 = (const float*)d_in[3];
    const float* W2 = (const float*)d_in[4];
    const float* b2 = (const float*)d_in[5];

    const int N = in_sizes[0] / 128;
    const int E = in_sizes[1] / 2;
    const int* esrc = ei;         // edge_index[0]
    const int* edst = ei + E;     // edge_index[1]

    char* ws = (char*)d_ws;
    size_t off = 0;
    auto alloc = [&](size_t bytes) -> void* {
        void* p = ws + off;
        off += (bytes + 255) & ~(size_t)255;
        return p;
    };
    float* h      = (float*)alloc((size_t)N * 128 * sizeof(float));
    float* dinv   = (float*)alloc((size_t)N * sizeof(float));
    int*   cnt    = (int*)  alloc((size_t)N * sizeof(int));
    int*   rowptr = (int*)  alloc((size_t)(N + 1) * sizeof(int));
    int*   cursor = (int*)  alloc((size_t)N * sizeof(int));
    int*   csrsrc = (int*)  alloc((size_t)E * sizeof(int));

    // --- graph preprocessing (per call: deterministic work, ws not preserved)
    hipMemsetAsync(cnt, 0, (size_t)N * sizeof(int), stream);
    count_kernel<<<(E + 255) / 256, 256, 0, stream>>>(edst, cnt, E);
    dinv_kernel<<<(N + 255) / 256, 256, 0, stream>>>(cnt, dinv, N);
    scan_kernel<<<1, 1024, 0, stream>>>(cnt, rowptr, cursor, N);
    scatter_kernel<<<(E + 255) / 256, 256, 0, stream>>>(esrc, edst, cursor, csrsrc, E);

    // --- layer 1: h = x@W1 ; d_out = relu(agg(h) + b1)
    gemm128_kernel<<<(N + 31) / 32, 256, 0, stream>>>(x, W1, h, N);
    agg_kernel<true><<<(N + 3) / 4, 256, 0, stream>>>(h, dinv, rowptr, csrsrc, b1,
                                                      (float*)d_out, N);

    // --- layer 2: h = d_out@W2 ; d_out = agg(h) + b2
    gemm128_kernel<<<(N + 31) / 32, 256, 0, stream>>>((const float*)d_out, W2, h, N);
    agg_kernel<false><<<(N + 3) / 4, 256, 0, stream>>>(h, dinv, rowptr, csrsrc, b2,
                                                       (float*)d_out, N);
}

// Round 2
// 592.890 us; speedup vs baseline: 1.1523x; 1.1523x over previous
//
#include <hip/hip_runtime.h>
#include <hip/hip_bf16.h>

// ---------------------------------------------------------------------------
// GCN encoder: 2x { h = x@W ; out[dst] += norm*h[src] (incl self-loop) ; +b ; relu? }
// norm = dinv[src]*dinv[dst], dinv = rsqrt(1 + indegree)
// CSR-by-dst built per call (histogram + hierarchical scan + atomic scatter).
// Per layer: fp32 GEMM (LDS W + x-tile, 4x4 reg tile), then gather-aggregate:
// 2 nodes per wave (float4/lane over 32-lane halves), edge batches staged in
// per-wave LDS, 4 gathers in flight per quad. Bias/ReLU fused.
// ---------------------------------------------------------------------------

#define CHUNK 2048

__global__ __launch_bounds__(256) void count_kernel(
    const int* __restrict__ dst, int* __restrict__ cnt, int E)
{
    int e = blockIdx.x * 256 + threadIdx.x;
    if (e < E) atomicAdd(&cnt[dst[e]], 1);
}

__global__ __launch_bounds__(256) void dinv_kernel(
    const int* __restrict__ cnt, float* __restrict__ dinv, int n)
{
    int i = blockIdx.x * 256 + threadIdx.x;
    if (i < n) dinv[i] = rsqrtf((float)(cnt[i] + 1));   // +1: self loop
}

// --- hierarchical scan: bsum (per-block totals) -> bscan (scan totals) ->
// --- rescan (full exclusive prefix, writes rowptr + cursor) ---------------
__global__ __launch_bounds__(256) void bsum_kernel(
    const int* __restrict__ cnt, int* __restrict__ bsum, int n)
{
    int base = blockIdx.x * CHUNK + threadIdx.x * 8;
    int s = 0;
    if (base + 8 <= n) {
        int4 a = *(const int4*)&cnt[base];
        int4 b = *(const int4*)&cnt[base + 4];
        s = a.x + a.y + a.z + a.w + b.x + b.y + b.z + b.w;
    } else {
        for (int k = 0; k < 8; ++k) if (base + k < n) s += cnt[base + k];
    }
    #pragma unroll
    for (int d = 1; d < 64; d <<= 1) s += __shfl_xor(s, d);
    __shared__ int ws[4];
    if ((threadIdx.x & 63) == 0) ws[threadIdx.x >> 6] = s;
    __syncthreads();
    if (threadIdx.x == 0) bsum[blockIdx.x] = ws[0] + ws[1] + ws[2] + ws[3];
}

__global__ __launch_bounds__(64) void bscan_kernel(int* bsum, int nb)
{
    int lane = threadIdx.x;          // nb <= 64 guaranteed (N <= 131072)
    int v = (lane < nb) ? bsum[lane] : 0;
    int x = v;
    #pragma unroll
    for (int d = 1; d < 64; d <<= 1) {
        int y = __shfl_up(x, d);
        if (lane >= d) x += y;
    }
    if (lane < nb) bsum[lane] = x - v;   // exclusive
}

__global__ __launch_bounds__(256) void rescan_kernel(
    const int* __restrict__ cnt, const int* __restrict__ bsum,
    int* __restrict__ rowptr, int* __restrict__ cursor, int n, int E)
{
    int t = threadIdx.x, lane = t & 63, wv = t >> 6;
    int base = blockIdx.x * CHUNK + t * 8;
    int v[8]; int s = 0;
    #pragma unroll
    for (int k = 0; k < 8; ++k) { v[k] = (base + k < n) ? cnt[base + k] : 0; s += v[k]; }
    int x = s;
    #pragma unroll
    for (int d = 1; d < 64; d <<= 1) {
        int y = __shfl_up(x, d);
        if (lane >= d) x += y;
    }
    __shared__ int ws[4];
    if (lane == 63) ws[wv] = x;
    __syncthreads();
    int wbase = 0;
    for (int i = 0; i < 4; ++i) if (i < wv) wbase += ws[i];
    int p = bsum[blockIdx.x] + wbase + (x - s);
    #pragma unroll
    for (int k = 0; k < 8; ++k) {
        if (base + k < n) { rowptr[base + k] = p; cursor[base + k] = p; }
        p += v[k];
    }
    if (blockIdx.x == 0 && t == 0) rowptr[n] = E;
}

__global__ __launch_bounds__(256) void scatter_kernel(
    const int* __restrict__ src, const int* __restrict__ dst,
    int* __restrict__ cursor, int* __restrict__ csrsrc, int E)
{
    int e = blockIdx.x * 256 + threadIdx.x;
    if (e < E) {
        int d = dst[e];
        int pos = atomicAdd(&cursor[d], 1);
        csrsrc[pos] = src[e];
    }
}

// out[M x 128] = A[M x 128] @ W[128 x 128], fp32.
__global__ __launch_bounds__(256) void gemm128_kernel(
    const float* __restrict__ A, const float* __restrict__ W,
    float* __restrict__ out, int M)
{
    __shared__ float Wl[128 * 128];
    __shared__ float Xt[128][32];            // Xt[k][r]
    const float4* W4 = (const float4*)W;
    float4* Wl4 = (float4*)Wl;
    #pragma unroll
    for (int j = 0; j < 16; ++j)
        Wl4[threadIdx.x + j * 256] = W4[threadIdx.x + j * 256];

    int row0 = blockIdx.x * 32;
    const float4* A4 = (const float4*)(A + (size_t)row0 * 128);
    #pragma unroll
    for (int j = 0; j < 4; ++j) {
        int i = threadIdx.x + j * 256;       // float4 index in 32x128 tile
        int r = i >> 5, c4 = i & 31;
        float4 v = A4[(size_t)r * 32 + c4];
        Xt[c4 * 4 + 0][r] = v.x; Xt[c4 * 4 + 1][r] = v.y;
        Xt[c4 * 4 + 2][r] = v.z; Xt[c4 * 4 + 3][r] = v.w;
    }
    __syncthreads();

    int cg = threadIdx.x & 31;               // 4 cols
    int rg = threadIdx.x >> 5;               // 4 rows
    float acc[4][4] = {};
    #pragma unroll 8
    for (int k = 0; k < 128; ++k) {
        float4 xv = *(const float4*)&Xt[k][rg * 4];
        float4 wv = *(const float4*)&Wl[k * 128 + cg * 4];
        acc[0][0] += xv.x * wv.x; acc[0][1] += xv.x * wv.y;
        acc[0][2] += xv.x * wv.z; acc[0][3] += xv.x * wv.w;
        acc[1][0] += xv.y * wv.x; acc[1][1] += xv.y * wv.y;
        acc[1][2] += xv.y * wv.z; acc[1][3] += xv.y * wv.w;
        acc[2][0] += xv.z * wv.x; acc[2][1] += xv.z * wv.y;
        acc[2][2] += xv.z * wv.z; acc[2][3] += xv.z * wv.w;
        acc[3][0] += xv.w * wv.x; acc[3][1] += xv.w * wv.y;
        acc[3][2] += xv.w * wv.z; acc[3][3] += xv.w * wv.w;
    }
    #pragma unroll
    for (int i2 = 0; i2 < 4; ++i2) {
        int row = row0 + rg * 4 + i2;
        if (row < M) {
            float4 o = make_float4(acc[i2][0], acc[i2][1], acc[i2][2], acc[i2][3]);
            *(float4*)&out[(size_t)row * 128 + cg * 4] = o;
        }
    }
}

// Aggregation: 2 nodes per wave; lane half (32 lanes) x float4 = 512B row.
// Edge batches of 32/node staged in per-wave LDS as {src, premult weight};
// inner loop processes 4 edges/quad with 4 independent row gathers in flight.
template <bool RELU>
__global__ __launch_bounds__(256) void agg_kernel(
    const float* __restrict__ h, const float* __restrict__ dinv,
    const int* __restrict__ rowptr, const int* __restrict__ csrsrc,
    const float* __restrict__ bias, float* __restrict__ out, int n)
{
    __shared__ int2 epair[4][64];            // [wave][slot] = {src, w bits}
    int wv = threadIdx.x >> 6;
    int lane = threadIdx.x & 63;
    int half = lane >> 5, sub = lane & 31;
    int node = (blockIdx.x * 4 + wv) * 2 + half;
    bool active = node < n;
    int nodeC = active ? node : (n - 1);

    const float4* h4 = (const float4*)h;
    float di = dinv[nodeC];
    int beg = rowptr[nodeC];
    int m = rowptr[nodeC + 1] - beg;

    float4 vs = h4[(size_t)nodeC * 32 + sub];
    float w0 = di * di;
    float4 acc;
    acc.x = vs.x * w0; acc.y = vs.y * w0; acc.z = vs.z * w0; acc.w = vs.w * w0;

    int mA = __shfl(m, 0), mB = __shfl(m, 32);
    int mmax = max(mA, mB);

    for (int eb = 0; eb < mmax; eb += 32) {
        int sl = 0; float dlw = 0.0f;
        if (active && (eb + sub) < m) {
            sl = csrsrc[beg + eb + sub];
            dlw = di * dinv[sl];
        }
        epair[wv][lane] = make_int2(sl, __float_as_int(dlw));
        int nq = mmax - eb; if (nq > 32) nq = 32;
        const int2* ep = &epair[wv][half * 32];
        for (int j = 0; j < nq; j += 4) {
            int2 p0 = ep[j + 0];
            int2 p1 = ep[j + 1];
            int2 p2 = ep[j + 2];
            int2 p3 = ep[j + 3];
            float4 v0 = h4[(size_t)p0.x * 32 + sub];
            float4 v1 = h4[(size_t)p1.x * 32 + sub];
            float4 v2 = h4[(size_t)p2.x * 32 + sub];
            float4 v3 = h4[(size_t)p3.x * 32 + sub];
            float w0f = __int_as_float(p0.y), w1f = __int_as_float(p1.y);
            float w2f = __int_as_float(p2.y), w3f = __int_as_float(p3.y);
            acc.x += v0.x * w0f; acc.y += v0.y * w0f; acc.z += v0.z * w0f; acc.w += v0.w * w0f;
            acc.x += v1.x * w1f; acc.y += v1.y * w1f; acc.z += v1.z * w1f; acc.w += v1.w * w1f;
            acc.x += v2.x * w2f; acc.y += v2.y * w2f; acc.z += v2.z * w2f; acc.w += v2.w * w2f;
            acc.x += v3.x * w3f; acc.y += v3.y * w3f; acc.z += v3.z * w3f; acc.w += v3.w * w3f;
        }
    }

    float4 bb = ((const float4*)bias)[sub];
    acc.x += bb.x; acc.y += bb.y; acc.z += bb.z; acc.w += bb.w;
    if (RELU) {
        acc.x = fmaxf(acc.x, 0.0f); acc.y = fmaxf(acc.y, 0.0f);
        acc.z = fmaxf(acc.z, 0.0f); acc.w = fmaxf(acc.w, 0.0f);
    }
    if (active) ((float4*)out)[(size_t)node * 32 + sub] = acc;
}

extern "C" void kernel_launch(void* const* d_in, const int* in_sizes, int n_in,
                              void* d_out, int out_size, void* d_ws, size_t ws_size,
                              hipStream_t stream)
{
    const float* x  = (const float*)d_in[0];
    const int*   ei = (const int*)d_in[1];
    const float* W1 = (const float*)d_in[2];
    const float* b1 = (const float*)d_in[3];
    const float* W2 = (const float*)d_in[4];
    const float* b2 = (const float*)d_in[5];

    const int N = in_sizes[0] / 128;
    const int E = in_sizes[1] / 2;
    const int* esrc = ei;         // edge_index[0]
    const int* edst = ei + E;     // edge_index[1]

    char* ws = (char*)d_ws;
    size_t off = 0;
    auto alloc = [&](size_t bytes) -> void* {
        void* p = ws + off;
        off += (bytes + 255) & ~(size_t)255;
        return p;
    };
    float* h      = (float*)alloc((size_t)N * 128 * sizeof(float));
    float* dinv   = (float*)alloc((size_t)N * sizeof(float));
    int*   cnt    = (int*)  alloc((size_t)N * sizeof(int));
    int*   rowptr = (int*)  alloc((size_t)(N + 1) * sizeof(int));
    int*   cursor = (int*)  alloc((size_t)N * sizeof(int));
    int*   csrsrc = (int*)  alloc((size_t)E * sizeof(int));
    int*   bsum   = (int*)  alloc(256 * sizeof(int));

    const int nb = (N + CHUNK - 1) / CHUNK;   // 49 for N=100000 (<= 64)

    // --- graph preprocessing
    hipMemsetAsync(cnt, 0, (size_t)N * sizeof(int), stream);
    count_kernel<<<(E + 255) / 256, 256, 0, stream>>>(edst, cnt, E);
    dinv_kernel<<<(N + 255) / 256, 256, 0, stream>>>(cnt, dinv, N);
    bsum_kernel<<<nb, 256, 0, stream>>>(cnt, bsum, N);
    bscan_kernel<<<1, 64, 0, stream>>>(bsum, nb);
    rescan_kernel<<<nb, 256, 0, stream>>>(cnt, bsum, rowptr, cursor, N, E);
    scatter_kernel<<<(E + 255) / 256, 256, 0, stream>>>(esrc, edst, cursor, csrsrc, E);

    // --- layer 1: h = x@W1 ; d_out = relu(agg(h) + b1)
    gemm128_kernel<<<(N + 31) / 32, 256, 0, stream>>>(x, W1, h, N);
    agg_kernel<true><<<(N + 7) / 8, 256, 0, stream>>>(h, dinv, rowptr, csrsrc, b1,
                                                      (float*)d_out, N);

    // --- layer 2: h = d_out@W2 ; d_out = agg(h) + b2
    gemm128_kernel<<<(N + 31) / 32, 256, 0, stream>>>((const float*)d_out, W2, h, N);
    agg_kernel<false><<<(N + 7) / 8, 256, 0, stream>>>(h, dinv, rowptr, csrsrc, b2,
                                                       (float*)d_out, N);
}

// Round 3
// 367.652 us; speedup vs baseline: 1.8583x; 1.6126x over previous
//
#include <hip/hip_runtime.h>
#include <hip/hip_bf16.h>

// ---------------------------------------------------------------------------
// GCN encoder: 2x { h = x@W ; out[dst] += norm*h[src] (incl self-loop) ; +b ; relu? }
// norm = dinv[src]*dinv[dst], dinv = rsqrt(1 + indegree)
//
// CSR build via bucket counting sort (buckets of 128 dst nodes):
//   A1 bucket_count : per-block LDS hist -> global bcnt[bucket*8+seg]
//   A2 scan_seg     : one-block exclusive scan (bucket-major) -> ptr/cur
//   A3 bucket_place : LDS hist + one global atomic per (block,bucket), then
//                     per-edge LDS-ranked write of (src,dst) pairs; each
//                     segment's cursor frontier stays L2-resident.
//   B  csr_finalize : per-bucket: LDS node hist + scan -> rowptr + dinv,
//                     LDS-staged placement -> fully coalesced csrsrc dump.
// Layers: fp32-accum GEMM (LDS W + x-tile, 4x4 reg tile) writing bf16 h;
// gather-aggregate reads bf16 rows (256B), fp32 accum, bias/ReLU fused.
// Layer-1 agg writes bf16 into d_out (scratch); layer-2 agg writes fp32 out.
// ---------------------------------------------------------------------------

#define NSEG 8
#define LHSZ 800          // max buckets (N <= 102400)
#define MAXB 4096         // LDS staging slots per bucket (avg 2048)

typedef unsigned int uint;
typedef unsigned short ushort;

static __device__ __forceinline__ float bfl(uint u) { return __uint_as_float(u << 16); }
static __device__ __forceinline__ float bfh(uint u) { return __uint_as_float(u & 0xffff0000u); }
static __device__ __forceinline__ uint f2bfu(float f) {
    __hip_bfloat16 b = __float2bfloat16(f);
    ushort u; __builtin_memcpy(&u, &b, 2); return (uint)u;
}

// --- A1: per-seg bucket histogram ------------------------------------------
__global__ __launch_bounds__(256) void bucket_count(
    const int* __restrict__ dst, int* __restrict__ bcnt, int E, int nb, int epb)
{
    __shared__ int lhist[LHSZ];
    int t = threadIdx.x;
    int seg = blockIdx.x & (NSEG - 1);
    int e0 = blockIdx.x * epb, e1 = min(E, e0 + epb);
    for (int i = t; i < nb; i += 256) lhist[i] = 0;
    __syncthreads();
    for (int e = e0 + t; e < e1; e += 256) atomicAdd(&lhist[dst[e] >> 7], 1);
    __syncthreads();
    for (int i = t; i < nb; i += 256) {
        int v = lhist[i];
        if (v) atomicAdd(&bcnt[i * NSEG + seg], v);
    }
}

// --- A2: one-block exclusive scan of bcnt (bucket-major), ptr + cursor -----
__global__ __launch_bounds__(256) void scan_seg(
    const int* __restrict__ bcnt, int* __restrict__ ptr, int* __restrict__ cur,
    int len, int E)
{
    __shared__ int ws[4];
    int t = threadIdx.x, lane = t & 63, wv = t >> 6;
    int base = 0;
    for (int s0 = 0; s0 < len; s0 += 256) {
        int i = s0 + t;
        int v = (i < len) ? bcnt[i] : 0;
        int x = v;
        #pragma unroll
        for (int d = 1; d < 64; d <<= 1) {
            int y = __shfl_up(x, d);
            if (lane >= d) x += y;
        }
        if (lane == 63) ws[wv] = x;
        __syncthreads();
        int wb = 0;
        for (int k = 0; k < wv; ++k) wb += ws[k];
        int excl = base + wb + (x - v);
        if (i < len) { ptr[i] = excl; cur[i] = excl; }
        base += ws[0] + ws[1] + ws[2] + ws[3];
        __syncthreads();
    }
    if (t == 0) ptr[len] = E;
}

// --- A3: place (src,dst) pairs in bucket-major order -----------------------
__global__ __launch_bounds__(256) void bucket_place(
    const int* __restrict__ src, const int* __restrict__ dst,
    int* __restrict__ cur, int2* __restrict__ pairs, int E, int nb, int epb)
{
    __shared__ int lhist[LHSZ];
    __shared__ int gb[LHSZ];
    int t = threadIdx.x;
    int seg = blockIdx.x & (NSEG - 1);
    int e0 = blockIdx.x * epb, e1 = min(E, e0 + epb);
    for (int i = t; i < nb; i += 256) lhist[i] = 0;
    __syncthreads();
    for (int e = e0 + t; e < e1; e += 256) atomicAdd(&lhist[dst[e] >> 7], 1);
    __syncthreads();
    for (int i = t; i < nb; i += 256) {
        int v = lhist[i];
        gb[i] = v ? atomicAdd(&cur[i * NSEG + seg], v) : 0;
        lhist[i] = 0;
    }
    __syncthreads();
    for (int e = e0 + t; e < e1; e += 256) {
        int d = dst[e];
        int b = d >> 7;
        int r = atomicAdd(&lhist[b], 1);
        pairs[gb[b] + r] = make_int2(src[e], d);
    }
}

// --- B: per-bucket CSR finalize + rowptr + dinv ----------------------------
__global__ __launch_bounds__(256) void csr_finalize(
    const int2* __restrict__ pairs, const int* __restrict__ ptr,
    int* __restrict__ rowptr, int* __restrict__ csrsrc,
    float* __restrict__ dinv, int N, int E)
{
    __shared__ int ncnt[128], sbuf[128], ncur[128];
    __shared__ int srcbuf[MAXB];
    int t = threadIdx.x;
    int b = blockIdx.x;
    int node0 = b << 7;
    int nn = min(128, N - node0);
    int base = ptr[b * NSEG], end = ptr[(b + 1) * NSEG];
    int len = end - base;

    if (t < 128) ncnt[t] = 0;
    __syncthreads();
    for (int i = t; i < len; i += 256) {
        int2 p = pairs[base + i];
        atomicAdd(&ncnt[p.y - node0], 1);
    }
    __syncthreads();
    if (t < 128) sbuf[t] = ncnt[t];
    __syncthreads();
    for (int d = 1; d < 128; d <<= 1) {
        int v = 0;
        if (t < 128 && t >= d) v = sbuf[t - d];
        __syncthreads();
        if (t < 128) sbuf[t] += v;
        __syncthreads();
    }
    if (t < 128) {
        int excl = sbuf[t] - ncnt[t];
        ncur[t] = excl;
        if (t < nn) {
            rowptr[node0 + t] = base + excl;
            dinv[node0 + t] = rsqrtf((float)(ncnt[t] + 1));
        }
    }
    __syncthreads();
    bool staged = (len <= MAXB);
    for (int i = t; i < len; i += 256) {
        int2 p = pairs[base + i];
        int pos = atomicAdd(&ncur[p.y - node0], 1);
        if (staged) srcbuf[pos] = p.x;
        else        csrsrc[base + pos] = p.x;
    }
    __syncthreads();
    if (staged)
        for (int i = t; i < len; i += 256) csrsrc[base + i] = srcbuf[i];
    if (b == 0 && t == 0) rowptr[N] = E;
}

// --- GEMM: out_bf16[M x 128] = A[M x 128] @ W[128 x 128], fp32 accumulate --
template <bool INBF>
__global__ __launch_bounds__(256) void gemm128_kernel(
    const void* __restrict__ Ap, const float* __restrict__ W,
    ushort* __restrict__ out, int M)
{
    __shared__ float Wl[128 * 128];
    __shared__ float Xt[128][32];            // Xt[k][r]
    const float4* W4 = (const float4*)W;
    float4* Wl4 = (float4*)Wl;
    #pragma unroll
    for (int j = 0; j < 16; ++j)
        Wl4[threadIdx.x + j * 256] = W4[threadIdx.x + j * 256];

    int row0 = blockIdx.x * 32;
    if (!INBF) {
        const float4* A4 = (const float4*)((const float*)Ap + (size_t)row0 * 128);
        #pragma unroll
        for (int j = 0; j < 4; ++j) {
            int i = threadIdx.x + j * 256;
            int r = i >> 5, g = i & 31;
            float4 v = A4[(size_t)r * 32 + g];
            Xt[g * 4 + 0][r] = v.x; Xt[g * 4 + 1][r] = v.y;
            Xt[g * 4 + 2][r] = v.z; Xt[g * 4 + 3][r] = v.w;
        }
    } else {
        const uint2* A2 = (const uint2*)((const ushort*)Ap + (size_t)row0 * 128);
        #pragma unroll
        for (int j = 0; j < 4; ++j) {
            int i = threadIdx.x + j * 256;
            int r = i >> 5, g = i & 31;
            uint2 v = A2[(size_t)r * 32 + g];
            Xt[g * 4 + 0][r] = bfl(v.x); Xt[g * 4 + 1][r] = bfh(v.x);
            Xt[g * 4 + 2][r] = bfl(v.y); Xt[g * 4 + 3][r] = bfh(v.y);
        }
    }
    __syncthreads();

    int cg = threadIdx.x & 31;               // 4 cols
    int rg = threadIdx.x >> 5;               // 4 rows
    float acc[4][4] = {};
    #pragma unroll 8
    for (int k = 0; k < 128; ++k) {
        float4 xv = *(const float4*)&Xt[k][rg * 4];
        float4 wv = *(const float4*)&Wl[k * 128 + cg * 4];
        acc[0][0] += xv.x * wv.x; acc[0][1] += xv.x * wv.y;
        acc[0][2] += xv.x * wv.z; acc[0][3] += xv.x * wv.w;
        acc[1][0] += xv.y * wv.x; acc[1][1] += xv.y * wv.y;
        acc[1][2] += xv.y * wv.z; acc[1][3] += xv.y * wv.w;
        acc[2][0] += xv.z * wv.x; acc[2][1] += xv.z * wv.y;
        acc[2][2] += xv.z * wv.z; acc[2][3] += xv.z * wv.w;
        acc[3][0] += xv.w * wv.x; acc[3][1] += xv.w * wv.y;
        acc[3][2] += xv.w * wv.z; acc[3][3] += xv.w * wv.w;
    }
    #pragma unroll
    for (int i2 = 0; i2 < 4; ++i2) {
        int row = row0 + rg * 4 + i2;
        if (row < M) {
            uint2 o;
            o.x = f2bfu(acc[i2][0]) | (f2bfu(acc[i2][1]) << 16);
            o.y = f2bfu(acc[i2][2]) | (f2bfu(acc[i2][3]) << 16);
            *(uint2*)&out[(size_t)row * 128 + cg * 4] = o;
        }
    }
}

// --- Aggregation: 2 nodes/wave, bf16 rows (8B/lane over 32-lane halves) ----
template <bool RELU, bool OUTBF>
__global__ __launch_bounds__(256) void agg_kernel(
    const ushort* __restrict__ h, const float* __restrict__ dinv,
    const int* __restrict__ rowptr, const int* __restrict__ csrsrc,
    const float* __restrict__ bias, void* __restrict__ outv, int n)
{
    __shared__ int2 epair[4][64];
    int wv = threadIdx.x >> 6;
    int lane = threadIdx.x & 63;
    int half = lane >> 5, sub = lane & 31;
    int node = (blockIdx.x * 4 + wv) * 2 + half;
    bool active = node < n;
    int nodeC = active ? node : (n - 1);

    const uint2* h2 = (const uint2*)h;
    float di = dinv[nodeC];
    int beg = rowptr[nodeC];
    int m = rowptr[nodeC + 1] - beg;

    uint2 vs = h2[(size_t)nodeC * 32 + sub];
    float w0 = di * di;
    float4 acc;
    acc.x = bfl(vs.x) * w0; acc.y = bfh(vs.x) * w0;
    acc.z = bfl(vs.y) * w0; acc.w = bfh(vs.y) * w0;

    int mA = __shfl(m, 0), mB = __shfl(m, 32);
    int mmax = max(mA, mB);

    for (int eb = 0; eb < mmax; eb += 32) {
        int sl = 0; float dlw = 0.0f;
        if (active && (eb + sub) < m) {
            sl = csrsrc[beg + eb + sub];
            dlw = di * dinv[sl];
        }
        epair[wv][lane] = make_int2(sl, __float_as_int(dlw));
        int nq = mmax - eb; if (nq > 32) nq = 32;
        const int2* ep = &epair[wv][half * 32];
        for (int j = 0; j < nq; j += 4) {
            int2 p0 = ep[j + 0];
            int2 p1 = ep[j + 1];
            int2 p2 = ep[j + 2];
            int2 p3 = ep[j + 3];
            uint2 v0 = h2[(size_t)p0.x * 32 + sub];
            uint2 v1 = h2[(size_t)p1.x * 32 + sub];
            uint2 v2 = h2[(size_t)p2.x * 32 + sub];
            uint2 v3 = h2[(size_t)p3.x * 32 + sub];
            float w0f = __int_as_float(p0.y), w1f = __int_as_float(p1.y);
            float w2f = __int_as_float(p2.y), w3f = __int_as_float(p3.y);
            acc.x += bfl(v0.x) * w0f; acc.y += bfh(v0.x) * w0f;
            acc.z += bfl(v0.y) * w0f; acc.w += bfh(v0.y) * w0f;
            acc.x += bfl(v1.x) * w1f; acc.y += bfh(v1.x) * w1f;
            acc.z += bfl(v1.y) * w1f; acc.w += bfh(v1.y) * w1f;
            acc.x += bfl(v2.x) * w2f; acc.y += bfh(v2.x) * w2f;
            acc.z += bfl(v2.y) * w2f; acc.w += bfh(v2.y) * w2f;
            acc.x += bfl(v3.x) * w3f; acc.y += bfh(v3.x) * w3f;
            acc.z += bfl(v3.y) * w3f; acc.w += bfh(v3.y) * w3f;
        }
    }

    float4 bb = ((const float4*)bias)[sub];
    acc.x += bb.x; acc.y += bb.y; acc.z += bb.z; acc.w += bb.w;
    if (RELU) {
        acc.x = fmaxf(acc.x, 0.0f); acc.y = fmaxf(acc.y, 0.0f);
        acc.z = fmaxf(acc.z, 0.0f); acc.w = fmaxf(acc.w, 0.0f);
    }
    if (active) {
        if (OUTBF) {
            uint2 o;
            o.x = f2bfu(acc.x) | (f2bfu(acc.y) << 16);
            o.y = f2bfu(acc.z) | (f2bfu(acc.w) << 16);
            ((uint2*)outv)[(size_t)node * 32 + sub] = o;
        } else {
            ((float4*)outv)[(size_t)node * 32 + sub] = acc;
        }
    }
}

extern "C" void kernel_launch(void* const* d_in, const int* in_sizes, int n_in,
                              void* d_out, int out_size, void* d_ws, size_t ws_size,
                              hipStream_t stream)
{
    const float* x  = (const float*)d_in[0];
    const int*   ei = (const int*)d_in[1];
    const float* W1 = (const float*)d_in[2];
    const float* b1 = (const float*)d_in[3];
    const float* W2 = (const float*)d_in[4];
    const float* b2 = (const float*)d_in[5];

    const int N = in_sizes[0] / 128;
    const int E = in_sizes[1] / 2;
    const int* esrc = ei;         // edge_index[0]
    const int* edst = ei + E;     // edge_index[1]
    const int nb = (N + 127) >> 7;           // 782 buckets

    char* ws = (char*)d_ws;
    size_t off = 0;
    auto alloc = [&](size_t bytes) -> void* {
        void* p = ws + off;
        off += (bytes + 255) & ~(size_t)255;
        return p;
    };
    ushort* h      = (ushort*)alloc((size_t)N * 128 * sizeof(ushort));   // bf16 h
    int2*   pairs  = (int2*)  alloc((size_t)E * sizeof(int2));
    int*    csrsrc = (int*)   alloc((size_t)E * sizeof(int));
    int*    rowptr = (int*)   alloc((size_t)(N + 1) * sizeof(int));
    float*  dinv   = (float*) alloc((size_t)N * sizeof(float));
    int*    bcnt   = (int*)   alloc((size_t)(NSEG * nb) * sizeof(int));
    int*    ptr    = (int*)   alloc((size_t)(NSEG * nb + 1) * sizeof(int));
    int*    cur    = (int*)   alloc((size_t)(NSEG * nb) * sizeof(int));

    const int gridA = 512;
    const int epb = (E + gridA - 1) / gridA;

    // --- CSR build
    hipMemsetAsync(bcnt, 0, (size_t)(NSEG * nb) * sizeof(int), stream);
    bucket_count<<<gridA, 256, 0, stream>>>(edst, bcnt, E, nb, epb);
    scan_seg<<<1, 256, 0, stream>>>(bcnt, ptr, cur, NSEG * nb, E);
    bucket_place<<<gridA, 256, 0, stream>>>(esrc, edst, cur, pairs, E, nb, epb);
    csr_finalize<<<nb, 256, 0, stream>>>(pairs, ptr, rowptr, csrsrc, dinv, N, E);

    // --- layer 1: h = bf16(x@W1) ; d_out(bf16 scratch) = relu(agg(h) + b1)
    gemm128_kernel<false><<<(N + 31) / 32, 256, 0, stream>>>(x, W1, h, N);
    agg_kernel<true, true><<<(N + 7) / 8, 256, 0, stream>>>(h, dinv, rowptr, csrsrc,
                                                            b1, d_out, N);

    // --- layer 2: h = bf16(d_out@W2) ; d_out = agg(h) + b2 (fp32)
    gemm128_kernel<true><<<(N + 31) / 32, 256, 0, stream>>>(d_out, W2, h, N);
    agg_kernel<false, false><<<(N + 7) / 8, 256, 0, stream>>>(h, dinv, rowptr, csrsrc,
                                                              b2, d_out, N);
}

// Round 4
// 303.566 us; speedup vs baseline: 2.2506x; 1.2111x over previous
//
#include <hip/hip_runtime.h>
#include <hip/hip_bf16.h>

// ---------------------------------------------------------------------------
// GCN encoder: 2x { h = x@W ; out[dst] += norm*h[src] (incl self-loop) ; +b ; relu? }
// norm = dinv[src]*dinv[dst], dinv = rsqrt(1 + indegree)
//
// CSR build via bucket counting sort (buckets of 128 dst nodes).
// GEMM via MFMA bf16 with split-precision (hi+lo bf16 ~= fp32):
//   layer1: Ahi*Bhi + Ahi*Blo + Alo*Bhi   (A = fp32 x, split in-register)
//   layer2: A*Bhi + A*Blo                 (A already bf16)
// W staged in LDS transposed (Wt[n][k]) + XOR-swizzled for conflict-free
// ds_read_b128 B-fragments. h stored bf16 (256B rows) for the gather phase.
// ---------------------------------------------------------------------------

#define NSEG 8
#define LHSZ 800          // max buckets (N <= 102400)
#define MAXB 4096         // LDS staging slots per bucket (avg 2048)

typedef unsigned int uint;
typedef unsigned short ushort;
typedef __attribute__((ext_vector_type(8))) short bf16x8;
typedef __attribute__((ext_vector_type(4))) float f32x4;

static __device__ __forceinline__ float bfl(uint u) { return __uint_as_float(u << 16); }
static __device__ __forceinline__ float bfh(uint u) { return __uint_as_float(u & 0xffff0000u); }
static __device__ __forceinline__ ushort f2bfu(float f) {
    __hip_bfloat16 b = __float2bfloat16(f);
    ushort u; __builtin_memcpy(&u, &b, 2); return u;
}
static __device__ __forceinline__ void split2(float f, ushort& h, ushort& l) {
    ushort hh = f2bfu(f);
    float hf = __uint_as_float(((uint)hh) << 16);
    h = hh; l = f2bfu(f - hf);
}

// --- A1: per-seg bucket histogram ------------------------------------------
__global__ __launch_bounds__(256) void bucket_count(
    const int* __restrict__ dst, int* __restrict__ bcnt, int E, int nb, int epb)
{
    __shared__ int lhist[LHSZ];
    int t = threadIdx.x;
    int seg = blockIdx.x & (NSEG - 1);
    int e0 = blockIdx.x * epb, e1 = min(E, e0 + epb);
    for (int i = t; i < nb; i += 256) lhist[i] = 0;
    __syncthreads();
    for (int e = e0 + t; e < e1; e += 256) atomicAdd(&lhist[dst[e] >> 7], 1);
    __syncthreads();
    for (int i = t; i < nb; i += 256) {
        int v = lhist[i];
        if (v) atomicAdd(&bcnt[i * NSEG + seg], v);
    }
}

// --- A2: one-block exclusive scan of bcnt (bucket-major), ptr + cursor -----
__global__ __launch_bounds__(256) void scan_seg(
    const int* __restrict__ bcnt, int* __restrict__ ptr, int* __restrict__ cur,
    int len, int E)
{
    __shared__ int ws[4];
    int t = threadIdx.x, lane = t & 63, wv = t >> 6;
    int base = 0;
    for (int s0 = 0; s0 < len; s0 += 256) {
        int i = s0 + t;
        int v = (i < len) ? bcnt[i] : 0;
        int x = v;
        #pragma unroll
        for (int d = 1; d < 64; d <<= 1) {
            int y = __shfl_up(x, d);
            if (lane >= d) x += y;
        }
        if (lane == 63) ws[wv] = x;
        __syncthreads();
        int wb = 0;
        for (int k = 0; k < wv; ++k) wb += ws[k];
        int excl = base + wb + (x - v);
        if (i < len) { ptr[i] = excl; cur[i] = excl; }
        base += ws[0] + ws[1] + ws[2] + ws[3];
        __syncthreads();
    }
    if (t == 0) ptr[len] = E;
}

// --- A3: place (src,dst) pairs in bucket-major order -----------------------
__global__ __launch_bounds__(256) void bucket_place(
    const int* __restrict__ src, const int* __restrict__ dst,
    int* __restrict__ cur, int2* __restrict__ pairs, int E, int nb, int epb)
{
    __shared__ int lhist[LHSZ];
    __shared__ int gb[LHSZ];
    int t = threadIdx.x;
    int seg = blockIdx.x & (NSEG - 1);
    int e0 = blockIdx.x * epb, e1 = min(E, e0 + epb);
    for (int i = t; i < nb; i += 256) lhist[i] = 0;
    __syncthreads();
    for (int e = e0 + t; e < e1; e += 256) atomicAdd(&lhist[dst[e] >> 7], 1);
    __syncthreads();
    for (int i = t; i < nb; i += 256) {
        int v = lhist[i];
        gb[i] = v ? atomicAdd(&cur[i * NSEG + seg], v) : 0;
        lhist[i] = 0;
    }
    __syncthreads();
    for (int e = e0 + t; e < e1; e += 256) {
        int d = dst[e];
        int b = d >> 7;
        int r = atomicAdd(&lhist[b], 1);
        pairs[gb[b] + r] = make_int2(src[e], d);
    }
}

// --- B: per-bucket CSR finalize + rowptr + dinv ----------------------------
__global__ __launch_bounds__(256) void csr_finalize(
    const int2* __restrict__ pairs, const int* __restrict__ ptr,
    int* __restrict__ rowptr, int* __restrict__ csrsrc,
    float* __restrict__ dinv, int N, int E)
{
    __shared__ int ncnt[128], sbuf[128], ncur[128];
    __shared__ int srcbuf[MAXB];
    int t = threadIdx.x;
    int b = blockIdx.x;
    int node0 = b << 7;
    int nn = min(128, N - node0);
    int base = ptr[b * NSEG], end = ptr[(b + 1) * NSEG];
    int len = end - base;

    if (t < 128) ncnt[t] = 0;
    __syncthreads();
    for (int i = t; i < len; i += 256) {
        int2 p = pairs[base + i];
        atomicAdd(&ncnt[p.y - node0], 1);
    }
    __syncthreads();
    if (t < 128) sbuf[t] = ncnt[t];
    __syncthreads();
    for (int d = 1; d < 128; d <<= 1) {
        int v = 0;
        if (t < 128 && t >= d) v = sbuf[t - d];
        __syncthreads();
        if (t < 128) sbuf[t] += v;
        __syncthreads();
    }
    if (t < 128) {
        int excl = sbuf[t] - ncnt[t];
        ncur[t] = excl;
        if (t < nn) {
            rowptr[node0 + t] = base + excl;
            dinv[node0 + t] = rsqrtf((float)(ncnt[t] + 1));
        }
    }
    __syncthreads();
    bool staged = (len <= MAXB);
    for (int i = t; i < len; i += 256) {
        int2 p = pairs[base + i];
        int pos = atomicAdd(&ncur[p.y - node0], 1);
        if (staged) srcbuf[pos] = p.x;
        else        csrsrc[base + pos] = p.x;
    }
    __syncthreads();
    if (staged)
        for (int i = t; i < len; i += 256) csrsrc[base + i] = srcbuf[i];
    if (b == 0 && t == 0) rowptr[N] = E;
}

// --- MFMA GEMM: out_bf16[M x 128] = A[M x 128] @ W[128 x 128] --------------
// MODE 0: A fp32, split hi/lo (3 mfma);  MODE 1: A bf16 (2 mfma).
// Block = 256 thr (4 waves) x 128 rows; wave w owns rows [w*32, w*32+32).
// LDS: Wt transposed+split: hi at [n*128+k]^swz, lo at +16384 (64KB).
template <int MODE>
__global__ __launch_bounds__(256) void gemm_mfma(
    const void* __restrict__ Ap, const float* __restrict__ W,
    ushort* __restrict__ out, int M)
{
    __shared__ ushort Wt[2 * 128 * 128];
    int t = threadIdx.x;

    // stage W: read fp32 row-major [k][n], split, store transposed+swizzled
    const float4* W4 = (const float4*)W;
    #pragma unroll
    for (int j = 0; j < 16; ++j) {
        int f = t + j * 256;                 // float4 index
        float4 v = W4[f];
        int e = f * 4;
        int k = e >> 7, n = e & 127;
        float vv[4] = {v.x, v.y, v.z, v.w};
        #pragma unroll
        for (int c = 0; c < 4; ++c) {
            int nn = n + c;
            ushort hi, lo; split2(vv[c], hi, lo);
            int I = (nn * 128 + k) ^ ((nn & 7) << 3);
            Wt[I] = hi; Wt[I + 16384] = lo;
        }
    }
    __syncthreads();

    int wv = t >> 6, lane = t & 63;
    int g = lane >> 4;                       // 0..3 : k-subgroup / D row group
    int lr = lane & 15;                      // A row / B col / D col
    int rowbase = blockIdx.x * 128 + wv * 32;
    int r0 = rowbase + lr, r1 = r0 + 16;
    int rc0 = min(r0, M - 1), rc1 = min(r1, M - 1);

    f32x4 acc[2][8];
    #pragma unroll
    for (int rt = 0; rt < 2; ++rt)
        #pragma unroll
        for (int ct = 0; ct < 8; ++ct)
            acc[rt][ct] = (f32x4)0.0f;

    #pragma unroll
    for (int ks = 0; ks < 4; ++ks) {
        int kof = ks * 32 + g * 8;
        bf16x8 ahi[2], alo[2];
        if (MODE == 0) {
            const float* A = (const float*)Ap;
            #pragma unroll
            for (int rt = 0; rt < 2; ++rt) {
                const float4* p = (const float4*)(A + (size_t)(rt ? rc1 : rc0) * 128 + kof);
                float4 u0 = p[0], u1 = p[1];
                ushort h0,l0,h1,l1,h2,l2,h3,l3,h4,l4,h5,l5,h6,l6,h7,l7;
                split2(u0.x,h0,l0); split2(u0.y,h1,l1); split2(u0.z,h2,l2); split2(u0.w,h3,l3);
                split2(u1.x,h4,l4); split2(u1.y,h5,l5); split2(u1.z,h6,l6); split2(u1.w,h7,l7);
                bf16x8 ah, al;
                ah[0]=(short)h0; ah[1]=(short)h1; ah[2]=(short)h2; ah[3]=(short)h3;
                ah[4]=(short)h4; ah[5]=(short)h5; ah[6]=(short)h6; ah[7]=(short)h7;
                al[0]=(short)l0; al[1]=(short)l1; al[2]=(short)l2; al[3]=(short)l3;
                al[4]=(short)l4; al[5]=(short)l5; al[6]=(short)l6; al[7]=(short)l7;
                ahi[rt] = ah; alo[rt] = al;
            }
        } else {
            const ushort* A = (const ushort*)Ap;
            ahi[0] = *(const bf16x8*)(A + (size_t)rc0 * 128 + kof);
            ahi[1] = *(const bf16x8*)(A + (size_t)rc1 * 128 + kof);
        }
        #pragma unroll
        for (int ct = 0; ct < 8; ++ct) {
            int n = ct * 16 + lr;
            int I = (n * 128 + kof) ^ ((n & 7) << 3);
            bf16x8 bhi = *(const bf16x8*)&Wt[I];
            bf16x8 blo = *(const bf16x8*)&Wt[I + 16384];
            #pragma unroll
            for (int rt = 0; rt < 2; ++rt) {
                acc[rt][ct] = __builtin_amdgcn_mfma_f32_16x16x32_bf16(ahi[rt], bhi, acc[rt][ct], 0, 0, 0);
                acc[rt][ct] = __builtin_amdgcn_mfma_f32_16x16x32_bf16(ahi[rt], blo, acc[rt][ct], 0, 0, 0);
                if (MODE == 0)
                    acc[rt][ct] = __builtin_amdgcn_mfma_f32_16x16x32_bf16(alo[rt], bhi, acc[rt][ct], 0, 0, 0);
            }
        }
    }

    // epilogue: D row = g*4 + r, col = lr (per 16x16 tile)
    #pragma unroll
    for (int rt = 0; rt < 2; ++rt) {
        #pragma unroll
        for (int r = 0; r < 4; ++r) {
            int row = rowbase + rt * 16 + g * 4 + r;
            if (row < M) {
                #pragma unroll
                for (int ct = 0; ct < 8; ++ct)
                    out[(size_t)row * 128 + ct * 16 + lr] = f2bfu(acc[rt][ct][r]);
            }
        }
    }
}

// --- Aggregation: 2 nodes/wave, bf16 rows (8B/lane over 32-lane halves) ----
template <bool RELU, bool OUTBF>
__global__ __launch_bounds__(256) void agg_kernel(
    const ushort* __restrict__ h, const float* __restrict__ dinv,
    const int* __restrict__ rowptr, const int* __restrict__ csrsrc,
    const float* __restrict__ bias, void* __restrict__ outv, int n)
{
    __shared__ int2 epair[4][64];
    int wv = threadIdx.x >> 6;
    int lane = threadIdx.x & 63;
    int half = lane >> 5, sub = lane & 31;
    int node = (blockIdx.x * 4 + wv) * 2 + half;
    bool active = node < n;
    int nodeC = active ? node : (n - 1);

    const uint2* h2 = (const uint2*)h;
    float di = dinv[nodeC];
    int beg = rowptr[nodeC];
    int m = rowptr[nodeC + 1] - beg;

    uint2 vs = h2[(size_t)nodeC * 32 + sub];
    float w0 = di * di;
    float4 acc;
    acc.x = bfl(vs.x) * w0; acc.y = bfh(vs.x) * w0;
    acc.z = bfl(vs.y) * w0; acc.w = bfh(vs.y) * w0;

    int mA = __shfl(m, 0), mB = __shfl(m, 32);
    int mmax = max(mA, mB);

    for (int eb = 0; eb < mmax; eb += 32) {
        int sl = 0; float dlw = 0.0f;
        if (active && (eb + sub) < m) {
            sl = csrsrc[beg + eb + sub];
            dlw = di * dinv[sl];
        }
        epair[wv][lane] = make_int2(sl, __float_as_int(dlw));
        int nq = mmax - eb; if (nq > 32) nq = 32;
        const int2* ep = &epair[wv][half * 32];
        for (int j = 0; j < nq; j += 4) {
            int2 p0 = ep[j + 0];
            int2 p1 = ep[j + 1];
            int2 p2 = ep[j + 2];
            int2 p3 = ep[j + 3];
            uint2 v0 = h2[(size_t)p0.x * 32 + sub];
            uint2 v1 = h2[(size_t)p1.x * 32 + sub];
            uint2 v2 = h2[(size_t)p2.x * 32 + sub];
            uint2 v3 = h2[(size_t)p3.x * 32 + sub];
            float w0f = __int_as_float(p0.y), w1f = __int_as_float(p1.y);
            float w2f = __int_as_float(p2.y), w3f = __int_as_float(p3.y);
            acc.x += bfl(v0.x) * w0f; acc.y += bfh(v0.x) * w0f;
            acc.z += bfl(v0.y) * w0f; acc.w += bfh(v0.y) * w0f;
            acc.x += bfl(v1.x) * w1f; acc.y += bfh(v1.x) * w1f;
            acc.z += bfl(v1.y) * w1f; acc.w += bfh(v1.y) * w1f;
            acc.x += bfl(v2.x) * w2f; acc.y += bfh(v2.x) * w2f;
            acc.z += bfl(v2.y) * w2f; acc.w += bfh(v2.y) * w2f;
            acc.x += bfl(v3.x) * w3f; acc.y += bfh(v3.x) * w3f;
            acc.z += bfl(v3.y) * w3f; acc.w += bfh(v3.y) * w3f;
        }
    }

    float4 bb = ((const float4*)bias)[sub];
    acc.x += bb.x; acc.y += bb.y; acc.z += bb.z; acc.w += bb.w;
    if (RELU) {
        acc.x = fmaxf(acc.x, 0.0f); acc.y = fmaxf(acc.y, 0.0f);
        acc.z = fmaxf(acc.z, 0.0f); acc.w = fmaxf(acc.w, 0.0f);
    }
    if (active) {
        if (OUTBF) {
            uint2 o;
            o.x = (uint)f2bfu(acc.x) | ((uint)f2bfu(acc.y) << 16);
            o.y = (uint)f2bfu(acc.z) | ((uint)f2bfu(acc.w) << 16);
            ((uint2*)outv)[(size_t)node * 32 + sub] = o;
        } else {
            ((float4*)outv)[(size_t)node * 32 + sub] = acc;
        }
    }
}

extern "C" void kernel_launch(void* const* d_in, const int* in_sizes, int n_in,
                              void* d_out, int out_size, void* d_ws, size_t ws_size,
                              hipStream_t stream)
{
    const float* x  = (const float*)d_in[0];
    const int*   ei = (const int*)d_in[1];
    const float* W1 = (const float*)d_in[2];
    const float* b1 = (const float*)d_in[3];
    const float* W2 = (const float*)d_in[4];
    const float* b2 = (const float*)d_in[5];

    const int N = in_sizes[0] / 128;
    const int E = in_sizes[1] / 2;
    const int* esrc = ei;         // edge_index[0]
    const int* edst = ei + E;     // edge_index[1]
    const int nb = (N + 127) >> 7;           // 782 buckets

    char* ws = (char*)d_ws;
    size_t off = 0;
    auto alloc = [&](size_t bytes) -> void* {
        void* p = ws + off;
        off += (bytes + 255) & ~(size_t)255;
        return p;
    };
    ushort* h      = (ushort*)alloc((size_t)N * 128 * sizeof(ushort));   // bf16 h
    int2*   pairs  = (int2*)  alloc((size_t)E * sizeof(int2));
    int*    csrsrc = (int*)   alloc((size_t)E * sizeof(int));
    int*    rowptr = (int*)   alloc((size_t)(N + 1) * sizeof(int));
    float*  dinv   = (float*) alloc((size_t)N * sizeof(float));
    int*    bcnt   = (int*)   alloc((size_t)(NSEG * nb) * sizeof(int));
    int*    ptr    = (int*)   alloc((size_t)(NSEG * nb + 1) * sizeof(int));
    int*    cur    = (int*)   alloc((size_t)(NSEG * nb) * sizeof(int));

    const int gridA = 512;
    const int epb = (E + gridA - 1) / gridA;

    // --- CSR build
    hipMemsetAsync(bcnt, 0, (size_t)(NSEG * nb) * sizeof(int), stream);
    bucket_count<<<gridA, 256, 0, stream>>>(edst, bcnt, E, nb, epb);
    scan_seg<<<1, 256, 0, stream>>>(bcnt, ptr, cur, NSEG * nb, E);
    bucket_place<<<gridA, 256, 0, stream>>>(esrc, edst, cur, pairs, E, nb, epb);
    csr_finalize<<<nb, 256, 0, stream>>>(pairs, ptr, rowptr, csrsrc, dinv, N, E);

    const int gemmGrid = (N + 127) / 128;

    // --- layer 1: h = bf16(x@W1) ; d_out(bf16 scratch) = relu(agg(h) + b1)
    gemm_mfma<0><<<gemmGrid, 256, 0, stream>>>(x, W1, h, N);
    agg_kernel<true, true><<<(N + 7) / 8, 256, 0, stream>>>(h, dinv, rowptr, csrsrc,
                                                            b1, d_out, N);

    // --- layer 2: h = bf16(d_out@W2) ; d_out = agg(h) + b2 (fp32)
    gemm_mfma<1><<<gemmGrid, 256, 0, stream>>>(d_out, W2, h, N);
    agg_kernel<false, false><<<(N + 7) / 8, 256, 0, stream>>>(h, dinv, rowptr, csrsrc,
                                                              b2, d_out, N);
}

// Round 5
// 249.024 us; speedup vs baseline: 2.7435x; 1.2190x over previous
//
#include <hip/hip_runtime.h>
#include <hip/hip_bf16.h>

// ---------------------------------------------------------------------------
// GCN encoder: 2x { h = x@W ; out[dst] += norm*h[src] (incl self-loop) ; +b ; relu? }
// norm = dinv[src]*dinv[dst], dinv = rsqrt(1 + indegree)
//
// CSR build via bucket counting sort (buckets of 128 dst nodes), pairs packed
// to 4B (src | dst_local<<20). bucket_count fused into the gemm1 dispatch.
// GEMM via MFMA bf16 split-precision; W pre-split ONCE into the swizzled LDS
// image (global, L2-hot) so per-block staging is a pure 64KB copy.
// Aggregate: 4 nodes/wave (16-lane groups), uint4 (16B/lane) row gathers,
// 8-deep unroll; LDS edge staging stride-17 (bank-conflict-free broadcasts).
// ---------------------------------------------------------------------------

#define NSEG 8
#define LHSZ 800          // max buckets (N <= 102400)
#define MAXB 4096         // LDS staging slots per bucket (avg 2048)

typedef unsigned int uint;
typedef unsigned short ushort;
typedef __attribute__((ext_vector_type(8))) short bf16x8;
typedef __attribute__((ext_vector_type(4))) float f32x4;

static __device__ __forceinline__ float bfl(uint u) { return __uint_as_float(u << 16); }
static __device__ __forceinline__ float bfh(uint u) { return __uint_as_float(u & 0xffff0000u); }
static __device__ __forceinline__ ushort f2bfu(float f) {
    __hip_bfloat16 b = __float2bfloat16(f);
    ushort u; __builtin_memcpy(&u, &b, 2); return u;
}
// truncation split: f = hi + r exactly at fp32; lo = trunc16(r) -> err ~2^-16|f|
static __device__ __forceinline__ void splitT(float f, ushort& h, ushort& l) {
    uint u = __float_as_uint(f);
    h = (ushort)(u >> 16);
    float r = f - __uint_as_float(u & 0xffff0000u);
    l = (ushort)(__float_as_uint(r) >> 16);
}

// --- K0: pre-split W1/W2 into swizzled LDS image + zero bcnt ---------------
__global__ __launch_bounds__(256) void wsplit_init(
    const float* __restrict__ W1, const float* __restrict__ W2,
    ushort* __restrict__ Ws1, ushort* __restrict__ Ws2,
    int* __restrict__ bcnt, int lenb)
{
    int tg = blockIdx.x * 256 + threadIdx.x;      // 0..32767
    int w = tg >> 14;
    int e = tg & 16383;
    int k = e >> 7, n = e & 127;
    float f = (w ? W2 : W1)[e];
    ushort hi, lo; splitT(f, hi, lo);
    int I = (n * 128 + k) ^ ((n & 7) << 3);
    ushort* o = w ? Ws2 : Ws1;
    o[I] = hi; o[I + 16384] = lo;
    if (tg < lenb) bcnt[tg] = 0;
}

// --- K2: one-block exclusive scan of bcnt (bucket-major), ptr + cursor -----
__global__ __launch_bounds__(1024) void scan_seg(
    const int* __restrict__ bcnt, int* __restrict__ ptr, int* __restrict__ cur,
    int len, int E)
{
    __shared__ int ws[16];
    int t = threadIdx.x, lane = t & 63, wv = t >> 6;
    int base = 0;
    for (int s0 = 0; s0 < len; s0 += 1024) {
        int i = s0 + t;
        int v = (i < len) ? bcnt[i] : 0;
        int x = v;
        #pragma unroll
        for (int d = 1; d < 64; d <<= 1) {
            int y = __shfl_up(x, d);
            if (lane >= d) x += y;
        }
        if (lane == 63) ws[wv] = x;
        __syncthreads();
        if (t < 16) {
            int sv = ws[t];
            #pragma unroll
            for (int d = 1; d < 16; d <<= 1) {
                int y = __shfl_up(sv, d);
                if (t >= d) sv += y;
            }
            ws[t] = sv;
        }
        __syncthreads();
        int wb = wv ? ws[wv - 1] : 0;
        int excl = base + wb + (x - v);
        if (i < len) { ptr[i] = excl; cur[i] = excl; }
        base += ws[15];
        __syncthreads();
    }
    if (t == 0) ptr[len] = E;
}

// --- K3: place packed (src | dlocal<<20) in bucket-major order -------------
__global__ __launch_bounds__(256) void bucket_place(
    const int* __restrict__ src, const int* __restrict__ dst,
    int* __restrict__ cur, uint* __restrict__ ppack, int E, int nb, int epb)
{
    __shared__ int lhist[LHSZ];
    __shared__ int gb[LHSZ];
    int t = threadIdx.x;
    int seg = blockIdx.x & (NSEG - 1);
    int e0 = blockIdx.x * epb, e1 = min(E, e0 + epb);
    for (int i = t; i < nb; i += 256) lhist[i] = 0;
    __syncthreads();
    for (int e = e0 + t; e < e1; e += 256) atomicAdd(&lhist[dst[e] >> 7], 1);
    __syncthreads();
    for (int i = t; i < nb; i += 256) {
        int v = lhist[i];
        gb[i] = v ? atomicAdd(&cur[i * NSEG + seg], v) : 0;
        lhist[i] = 0;
    }
    __syncthreads();
    for (int e = e0 + t; e < e1; e += 256) {
        int d = dst[e];
        int b = d >> 7;
        int r = atomicAdd(&lhist[b], 1);
        ppack[gb[b] + r] = (uint)src[e] | ((uint)(d & 127) << 20);
    }
}

// --- K4: per-bucket CSR finalize + rowptr + dinv ---------------------------
__global__ __launch_bounds__(256) void csr_finalize(
    const uint* __restrict__ ppack, const int* __restrict__ ptr,
    int* __restrict__ rowptr, int* __restrict__ csrsrc,
    float* __restrict__ dinv, int N, int E)
{
    __shared__ int ncnt[128], sbuf[128], ncur[128];
    __shared__ int srcbuf[MAXB];
    int t = threadIdx.x;
    int b = blockIdx.x;
    int node0 = b << 7;
    int nn = min(128, N - node0);
    int base = ptr[b * NSEG], end = ptr[(b + 1) * NSEG];
    int len = end - base;

    if (t < 128) ncnt[t] = 0;
    __syncthreads();
    for (int i = t; i < len; i += 256)
        atomicAdd(&ncnt[ppack[base + i] >> 20], 1);
    __syncthreads();
    if (t < 128) sbuf[t] = ncnt[t];
    __syncthreads();
    for (int d = 1; d < 128; d <<= 1) {
        int v = 0;
        if (t < 128 && t >= d) v = sbuf[t - d];
        __syncthreads();
        if (t < 128) sbuf[t] += v;
        __syncthreads();
    }
    if (t < 128) {
        int excl = sbuf[t] - ncnt[t];
        ncur[t] = excl;
        if (t < nn) {
            rowptr[node0 + t] = base + excl;
            dinv[node0 + t] = rsqrtf((float)(ncnt[t] + 1));
        }
    }
    __syncthreads();
    bool staged = (len <= MAXB);
    for (int i = t; i < len; i += 256) {
        uint p = ppack[base + i];
        int pos = atomicAdd(&ncur[p >> 20], 1);
        int sl = (int)(p & 0xFFFFFu);
        if (staged) srcbuf[pos] = sl;
        else        csrsrc[base + pos] = sl;
    }
    __syncthreads();
    if (staged)
        for (int i = t; i < len; i += 256) csrsrc[base + i] = srcbuf[i];
    if (b == 0 && t == 0) rowptr[N] = E;
}

// --- MFMA GEMM body: out_bf16[M x 128] = A @ W (Wsp = pre-split LDS image) -
// MODE 0: A fp32 (truncation hi/lo, 3 mfma); MODE 1: A bf16 (2 mfma).
template <int MODE>
static __device__ __forceinline__ void gemm_body(
    ushort* Wt, const void* __restrict__ Ap, const ushort* __restrict__ Wsp,
    ushort* __restrict__ out, int M, int blk)
{
    int t = threadIdx.x;
    {   // stage pre-split W image: pure 64KB copy
        const uint4* s4 = (const uint4*)Wsp;
        uint4* d4 = (uint4*)Wt;
        #pragma unroll
        for (int j = 0; j < 16; ++j)
            d4[t + j * 256] = s4[t + j * 256];
    }
    __syncthreads();

    int wv = t >> 6, lane = t & 63;
    int g = lane >> 4;                       // k-subgroup / D row group
    int lr = lane & 15;                      // A row / B col / D col
    int rowbase = blk * 128 + wv * 32;
    int r0 = rowbase + lr, r1 = r0 + 16;
    int rc0 = min(r0, M - 1), rc1 = min(r1, M - 1);

    f32x4 acc[2][8];
    #pragma unroll
    for (int rt = 0; rt < 2; ++rt)
        #pragma unroll
        for (int ct = 0; ct < 8; ++ct)
            acc[rt][ct] = (f32x4)0.0f;

    #pragma unroll
    for (int ks = 0; ks < 4; ++ks) {
        int kof = ks * 32 + g * 8;
        bf16x8 ahi[2], alo[2];
        if (MODE == 0) {
            const float* A = (const float*)Ap;
            #pragma unroll
            for (int rt = 0; rt < 2; ++rt) {
                const float4* p = (const float4*)(A + (size_t)(rt ? rc1 : rc0) * 128 + kof);
                float4 u0 = p[0], u1 = p[1];
                float uu[8] = {u0.x, u0.y, u0.z, u0.w, u1.x, u1.y, u1.z, u1.w};
                bf16x8 ah, al;
                #pragma unroll
                for (int q = 0; q < 8; ++q) {
                    ushort hh, ll; splitT(uu[q], hh, ll);
                    ah[q] = (short)hh; al[q] = (short)ll;
                }
                ahi[rt] = ah; alo[rt] = al;
            }
        } else {
            const ushort* A = (const ushort*)Ap;
            ahi[0] = *(const bf16x8*)(A + (size_t)rc0 * 128 + kof);
            ahi[1] = *(const bf16x8*)(A + (size_t)rc1 * 128 + kof);
        }
        #pragma unroll
        for (int ct = 0; ct < 8; ++ct) {
            int n = ct * 16 + lr;
            int I = (n * 128 + kof) ^ ((n & 7) << 3);
            bf16x8 bhi = *(const bf16x8*)&Wt[I];
            bf16x8 blo = *(const bf16x8*)&Wt[I + 16384];
            #pragma unroll
            for (int rt = 0; rt < 2; ++rt) {
                acc[rt][ct] = __builtin_amdgcn_mfma_f32_16x16x32_bf16(ahi[rt], bhi, acc[rt][ct], 0, 0, 0);
                acc[rt][ct] = __builtin_amdgcn_mfma_f32_16x16x32_bf16(ahi[rt], blo, acc[rt][ct], 0, 0, 0);
                if (MODE == 0)
                    acc[rt][ct] = __builtin_amdgcn_mfma_f32_16x16x32_bf16(alo[rt], bhi, acc[rt][ct], 0, 0, 0);
            }
        }
    }

    #pragma unroll
    for (int rt = 0; rt < 2; ++rt) {
        #pragma unroll
        for (int r = 0; r < 4; ++r) {
            int row = rowbase + rt * 16 + g * 4 + r;
            if (row < M) {
                #pragma unroll
                for (int ct = 0; ct < 8; ++ct)
                    out[(size_t)row * 128 + ct * 16 + lr] = f2bfu(acc[rt][ct][r]);
            }
        }
    }
}

template <int MODE>
__global__ __launch_bounds__(256) void gemm_mfma(
    const void* __restrict__ Ap, const ushort* __restrict__ Wsp,
    ushort* __restrict__ out, int M)
{
    __shared__ ushort Wt[2 * 128 * 128];
    gemm_body<MODE>(Wt, Ap, Wsp, out, M, blockIdx.x);
}

// --- K1: gemm1 (blocks < gemmGrid) fused with bucket_count (rest) ----------
__global__ __launch_bounds__(256) void gemm1_count(
    const float* __restrict__ x, const ushort* __restrict__ Wsp,
    ushort* __restrict__ h, int M, int gemmGrid,
    const int* __restrict__ dst, int* __restrict__ bcnt, int E, int nb, int epb)
{
    __shared__ ushort Wt[2 * 128 * 128];
    if ((int)blockIdx.x >= gemmGrid) {
        int* lhist = (int*)Wt;
        int b = blockIdx.x - gemmGrid;
        int t = threadIdx.x;
        int seg = b & (NSEG - 1);
        int e0 = b * epb, e1 = min(E, e0 + epb);
        for (int i = t; i < nb; i += 256) lhist[i] = 0;
        __syncthreads();
        for (int e = e0 + t; e < e1; e += 256) atomicAdd(&lhist[dst[e] >> 7], 1);
        __syncthreads();
        for (int i = t; i < nb; i += 256) {
            int v = lhist[i];
            if (v) atomicAdd(&bcnt[i * NSEG + seg], v);
        }
        return;
    }
    gemm_body<0>(Wt, x, Wsp, h, M, blockIdx.x);
}

// --- Aggregation: 4 nodes/wave (16-lane groups), uint4 row gathers ---------
#define FMA8(v, wgt) do { float wf_ = (wgt); \
    acc[0] += bfl((v).x) * wf_; acc[1] += bfh((v).x) * wf_; \
    acc[2] += bfl((v).y) * wf_; acc[3] += bfh((v).y) * wf_; \
    acc[4] += bfl((v).z) * wf_; acc[5] += bfh((v).z) * wf_; \
    acc[6] += bfl((v).w) * wf_; acc[7] += bfh((v).w) * wf_; } while (0)

template <bool RELU, bool OUTBF>
__global__ __launch_bounds__(256) void agg_kernel(
    const ushort* __restrict__ h, const float* __restrict__ dinv,
    const int* __restrict__ rowptr, const int* __restrict__ csrsrc,
    const float* __restrict__ bias, void* __restrict__ outv, int n)
{
    __shared__ int2 epair[4][4][17];         // stride 17: groups on distinct banks
    int t = threadIdx.x;
    int wv = t >> 6, lane = t & 63;
    int g = lane >> 4, s = lane & 15;
    int node = blockIdx.x * 16 + wv * 4 + g;
    bool active = node < n;
    int nodeC = active ? node : (n - 1);

    const uint4* h4 = (const uint4*)h;
    float di = dinv[nodeC];
    int beg = rowptr[nodeC];
    int m = active ? (rowptr[nodeC + 1] - beg) : 0;

    uint4 vs = h4[(size_t)nodeC * 16 + s];
    float acc[8];
    {
        float w0 = di * di;
        acc[0] = bfl(vs.x) * w0; acc[1] = bfh(vs.x) * w0;
        acc[2] = bfl(vs.y) * w0; acc[3] = bfh(vs.y) * w0;
        acc[4] = bfl(vs.z) * w0; acc[5] = bfh(vs.z) * w0;
        acc[6] = bfl(vs.w) * w0; acc[7] = bfh(vs.w) * w0;
    }

    int m0 = __shfl(m, 0), m1 = __shfl(m, 16), m2 = __shfl(m, 32), m3 = __shfl(m, 48);
    int mmax = max(max(m0, m1), max(m2, m3));

    for (int eb = 0; eb < mmax; eb += 16) {
        int sl = 0; float dlw = 0.0f;
        int idx = eb + s;
        if (idx < m) { sl = csrsrc[beg + idx]; dlw = di * dinv[sl]; }
        epair[wv][g][s] = make_int2(sl, __float_as_int(dlw));
        const int2* ep = epair[wv][g];
        #pragma unroll
        for (int j = 0; j < 16; j += 8) {
            int2 p0 = ep[j + 0], p1 = ep[j + 1], p2 = ep[j + 2], p3 = ep[j + 3];
            int2 p4 = ep[j + 4], p5 = ep[j + 5], p6 = ep[j + 6], p7 = ep[j + 7];
            uint4 v0 = h4[(size_t)(uint)p0.x * 16 + s];
            uint4 v1 = h4[(size_t)(uint)p1.x * 16 + s];
            uint4 v2 = h4[(size_t)(uint)p2.x * 16 + s];
            uint4 v3 = h4[(size_t)(uint)p3.x * 16 + s];
            uint4 v4 = h4[(size_t)(uint)p4.x * 16 + s];
            uint4 v5 = h4[(size_t)(uint)p5.x * 16 + s];
            uint4 v6 = h4[(size_t)(uint)p6.x * 16 + s];
            uint4 v7 = h4[(size_t)(uint)p7.x * 16 + s];
            FMA8(v0, __int_as_float(p0.y));
            FMA8(v1, __int_as_float(p1.y));
            FMA8(v2, __int_as_float(p2.y));
            FMA8(v3, __int_as_float(p3.y));
            FMA8(v4, __int_as_float(p4.y));
            FMA8(v5, __int_as_float(p5.y));
            FMA8(v6, __int_as_float(p6.y));
            FMA8(v7, __int_as_float(p7.y));
        }
    }

    const float4* b4 = (const float4*)bias;
    float4 ba = b4[s * 2], bb = b4[s * 2 + 1];
    acc[0] += ba.x; acc[1] += ba.y; acc[2] += ba.z; acc[3] += ba.w;
    acc[4] += bb.x; acc[5] += bb.y; acc[6] += bb.z; acc[7] += bb.w;
    if (RELU) {
        #pragma unroll
        for (int q = 0; q < 8; ++q) acc[q] = fmaxf(acc[q], 0.0f);
    }
    if (active) {
        if (OUTBF) {
            uint4 o;
            o.x = (uint)f2bfu(acc[0]) | ((uint)f2bfu(acc[1]) << 16);
            o.y = (uint)f2bfu(acc[2]) | ((uint)f2bfu(acc[3]) << 16);
            o.z = (uint)f2bfu(acc[4]) | ((uint)f2bfu(acc[5]) << 16);
            o.w = (uint)f2bfu(acc[6]) | ((uint)f2bfu(acc[7]) << 16);
            ((uint4*)outv)[(size_t)node * 16 + s] = o;
        } else {
            float4* o4 = (float4*)outv;
            o4[(size_t)node * 32 + s * 2]     = make_float4(acc[0], acc[1], acc[2], acc[3]);
            o4[(size_t)node * 32 + s * 2 + 1] = make_float4(acc[4], acc[5], acc[6], acc[7]);
        }
    }
}

extern "C" void kernel_launch(void* const* d_in, const int* in_sizes, int n_in,
                              void* d_out, int out_size, void* d_ws, size_t ws_size,
                              hipStream_t stream)
{
    const float* x  = (const float*)d_in[0];
    const int*   ei = (const int*)d_in[1];
    const float* W1 = (const float*)d_in[2];
    const float* b1 = (const float*)d_in[3];
    const float* W2 = (const float*)d_in[4];
    const float* b2 = (const float*)d_in[5];

    const int N = in_sizes[0] / 128;
    const int E = in_sizes[1] / 2;
    const int* esrc = ei;         // edge_index[0]
    const int* edst = ei + E;     // edge_index[1]
    const int nb = (N + 127) >> 7;           // 782 buckets

    char* ws = (char*)d_ws;
    size_t off = 0;
    auto alloc = [&](size_t bytes) -> void* {
        void* p = ws + off;
        off += (bytes + 255) & ~(size_t)255;
        return p;
    };
    ushort* h      = (ushort*)alloc((size_t)N * 128 * sizeof(ushort));   // bf16 h
    uint*   ppack  = (uint*)  alloc((size_t)E * sizeof(uint));
    int*    csrsrc = (int*)   alloc((size_t)E * sizeof(int));
    int*    rowptr = (int*)   alloc((size_t)(N + 1) * sizeof(int));
    float*  dinv   = (float*) alloc((size_t)N * sizeof(float));
    int*    bcnt   = (int*)   alloc((size_t)(NSEG * nb) * sizeof(int));
    int*    ptr    = (int*)   alloc((size_t)(NSEG * nb + 1) * sizeof(int));
    int*    cur    = (int*)   alloc((size_t)(NSEG * nb) * sizeof(int));
    ushort* Ws1    = (ushort*)alloc(2 * 128 * 128 * sizeof(ushort));
    ushort* Ws2    = (ushort*)alloc(2 * 128 * 128 * sizeof(ushort));

    const int gridA = 512;
    const int epb = (E + gridA - 1) / gridA;
    const int gemmGrid = (N + 127) / 128;

    // K0: W pre-split + bcnt zero
    wsplit_init<<<128, 256, 0, stream>>>(W1, W2, Ws1, Ws2, bcnt, NSEG * nb);
    // K1: gemm1 (x@W1 -> h bf16) fused with bucket_count
    gemm1_count<<<gemmGrid + gridA, 256, 0, stream>>>(x, Ws1, h, N, gemmGrid,
                                                      edst, bcnt, E, nb, epb);
    // K2-K4: scan, place, finalize
    scan_seg<<<1, 1024, 0, stream>>>(bcnt, ptr, cur, NSEG * nb, E);
    bucket_place<<<gridA, 256, 0, stream>>>(esrc, edst, cur, ppack, E, nb, epb);
    csr_finalize<<<nb, 256, 0, stream>>>(ppack, ptr, rowptr, csrsrc, dinv, N, E);
    // K5: layer-1 aggregate -> d_out (bf16 scratch)
    agg_kernel<true, true><<<(N + 15) / 16, 256, 0, stream>>>(h, dinv, rowptr, csrsrc,
                                                              b1, d_out, N);
    // K6: gemm2 (d_out@W2 -> h bf16)
    gemm_mfma<1><<<gemmGrid, 256, 0, stream>>>(d_out, Ws2, h, N);
    // K7: layer-2 aggregate -> d_out (fp32 final)
    agg_kernel<false, false><<<(N + 15) / 16, 256, 0, stream>>>(h, dinv, rowptr, csrsrc,
                                                                b2, d_out, N);
}

// Round 6
// 237.770 us; speedup vs baseline: 2.8733x; 1.0473x over previous
//
#include <hip/hip_runtime.h>
#include <hip/hip_bf16.h>

// ---------------------------------------------------------------------------
// GCN encoder: 2x { h = x@W ; out[dst] += norm*h[src] (incl self-loop) ; +b ; relu? }
// norm = dinv[src]*dinv[dst], dinv = rsqrt(1 + indegree)
//
// CSR build via bucket counting sort (buckets of 128 dst nodes), pairs packed
// to 4B (src | dst_local<<20). bucket_count fused into the gemm1 dispatch.
// GEMM via MFMA bf16 split-precision; W pre-split ONCE into the swizzled LDS
// image (global, L2-hot) so per-block staging is a pure 64KB copy.
// Aggregate: 2 nodes/wave (32-lane halves) x uint2 row gathers, nq-bounded
// 8-deep unroll, 1024-thread blocks (no barriers -> full 32-wave residency).
// ---------------------------------------------------------------------------

#define NSEG 8
#define LHSZ 800          // max buckets (N <= 102400)
#define MAXB 4096         // LDS staging slots per bucket (avg 2048)

typedef unsigned int uint;
typedef unsigned short ushort;
typedef __attribute__((ext_vector_type(8))) short bf16x8;
typedef __attribute__((ext_vector_type(4))) float f32x4;

static __device__ __forceinline__ float bfl(uint u) { return __uint_as_float(u << 16); }
static __device__ __forceinline__ float bfh(uint u) { return __uint_as_float(u & 0xffff0000u); }
static __device__ __forceinline__ ushort f2bfu(float f) {
    __hip_bfloat16 b = __float2bfloat16(f);
    ushort u; __builtin_memcpy(&u, &b, 2); return u;
}
// truncation split: f = hi + r exactly at fp32; lo = trunc16(r) -> err ~2^-16|f|
static __device__ __forceinline__ void splitT(float f, ushort& h, ushort& l) {
    uint u = __float_as_uint(f);
    h = (ushort)(u >> 16);
    float r = f - __uint_as_float(u & 0xffff0000u);
    l = (ushort)(__float_as_uint(r) >> 16);
}

// --- K0: pre-split W1/W2 into swizzled LDS image + zero bcnt ---------------
__global__ __launch_bounds__(256) void wsplit_init(
    const float* __restrict__ W1, const float* __restrict__ W2,
    ushort* __restrict__ Ws1, ushort* __restrict__ Ws2,
    int* __restrict__ bcnt, int lenb)
{
    int tg = blockIdx.x * 256 + threadIdx.x;      // 0..32767
    int w = tg >> 14;
    int e = tg & 16383;
    int k = e >> 7, n = e & 127;
    float f = (w ? W2 : W1)[e];
    ushort hi, lo; splitT(f, hi, lo);
    int I = (n * 128 + k) ^ ((n & 7) << 3);
    ushort* o = w ? Ws2 : Ws1;
    o[I] = hi; o[I + 16384] = lo;
    if (tg < lenb) bcnt[tg] = 0;
}

// --- K2: one-block exclusive scan of bcnt (bucket-major), ptr + cursor -----
__global__ __launch_bounds__(1024) void scan_seg(
    const int* __restrict__ bcnt, int* __restrict__ ptr, int* __restrict__ cur,
    int len, int E)
{
    __shared__ int ws[16];
    int t = threadIdx.x, lane = t & 63, wv = t >> 6;
    int base = 0;
    for (int s0 = 0; s0 < len; s0 += 1024) {
        int i = s0 + t;
        int v = (i < len) ? bcnt[i] : 0;
        int x = v;
        #pragma unroll
        for (int d = 1; d < 64; d <<= 1) {
            int y = __shfl_up(x, d);
            if (lane >= d) x += y;
        }
        if (lane == 63) ws[wv] = x;
        __syncthreads();
        if (t < 16) {
            int sv = ws[t];
            #pragma unroll
            for (int d = 1; d < 16; d <<= 1) {
                int y = __shfl_up(sv, d);
                if (t >= d) sv += y;
            }
            ws[t] = sv;
        }
        __syncthreads();
        int wb = wv ? ws[wv - 1] : 0;
        int excl = base + wb + (x - v);
        if (i < len) { ptr[i] = excl; cur[i] = excl; }
        base += ws[15];
        __syncthreads();
    }
    if (t == 0) ptr[len] = E;
}

// --- K3: place packed (src | dlocal<<20) in bucket-major order -------------
__global__ __launch_bounds__(256) void bucket_place(
    const int* __restrict__ src, const int* __restrict__ dst,
    int* __restrict__ cur, uint* __restrict__ ppack, int E, int nb, int epb)
{
    __shared__ int lhist[LHSZ];
    __shared__ int gb[LHSZ];
    int t = threadIdx.x;
    int seg = blockIdx.x & (NSEG - 1);
    int e0 = blockIdx.x * epb, e1 = min(E, e0 + epb);
    for (int i = t; i < nb; i += 256) lhist[i] = 0;
    __syncthreads();
    for (int e = e0 + t; e < e1; e += 256) atomicAdd(&lhist[dst[e] >> 7], 1);
    __syncthreads();
    for (int i = t; i < nb; i += 256) {
        int v = lhist[i];
        gb[i] = v ? atomicAdd(&cur[i * NSEG + seg], v) : 0;
        lhist[i] = 0;
    }
    __syncthreads();
    for (int e = e0 + t; e < e1; e += 256) {
        int d = dst[e];
        int b = d >> 7;
        int r = atomicAdd(&lhist[b], 1);
        ppack[gb[b] + r] = (uint)src[e] | ((uint)(d & 127) << 20);
    }
}

// --- K4: per-bucket CSR finalize + rowptr + dinv ---------------------------
__global__ __launch_bounds__(256) void csr_finalize(
    const uint* __restrict__ ppack, const int* __restrict__ ptr,
    int* __restrict__ rowptr, int* __restrict__ csrsrc,
    float* __restrict__ dinv, int N, int E)
{
    __shared__ int ncnt[128], sbuf[128], ncur[128];
    __shared__ int srcbuf[MAXB];
    int t = threadIdx.x;
    int b = blockIdx.x;
    int node0 = b << 7;
    int nn = min(128, N - node0);
    int base = ptr[b * NSEG], end = ptr[(b + 1) * NSEG];
    int len = end - base;

    if (t < 128) ncnt[t] = 0;
    __syncthreads();
    for (int i = t; i < len; i += 256)
        atomicAdd(&ncnt[ppack[base + i] >> 20], 1);
    __syncthreads();
    if (t < 128) sbuf[t] = ncnt[t];
    __syncthreads();
    for (int d = 1; d < 128; d <<= 1) {
        int v = 0;
        if (t < 128 && t >= d) v = sbuf[t - d];
        __syncthreads();
        if (t < 128) sbuf[t] += v;
        __syncthreads();
    }
    if (t < 128) {
        int excl = sbuf[t] - ncnt[t];
        ncur[t] = excl;
        if (t < nn) {
            rowptr[node0 + t] = base + excl;
            dinv[node0 + t] = rsqrtf((float)(ncnt[t] + 1));
        }
    }
    __syncthreads();
    bool staged = (len <= MAXB);
    for (int i = t; i < len; i += 256) {
        uint p = ppack[base + i];
        int pos = atomicAdd(&ncur[p >> 20], 1);
        int sl = (int)(p & 0xFFFFFu);
        if (staged) srcbuf[pos] = sl;
        else        csrsrc[base + pos] = sl;
    }
    __syncthreads();
    if (staged)
        for (int i = t; i < len; i += 256) csrsrc[base + i] = srcbuf[i];
    if (b == 0 && t == 0) rowptr[N] = E;
}

// --- MFMA GEMM body: out_bf16[M x 128] = A @ W (Wsp = pre-split LDS image) -
// MODE 0: A fp32 (truncation hi/lo, 3 mfma); MODE 1: A bf16 (2 mfma).
template <int MODE>
static __device__ __forceinline__ void gemm_body(
    ushort* Wt, const void* __restrict__ Ap, const ushort* __restrict__ Wsp,
    ushort* __restrict__ out, int M, int blk)
{
    int t = threadIdx.x;
    {   // stage pre-split W image: pure 64KB copy
        const uint4* s4 = (const uint4*)Wsp;
        uint4* d4 = (uint4*)Wt;
        #pragma unroll
        for (int j = 0; j < 16; ++j)
            d4[t + j * 256] = s4[t + j * 256];
    }
    __syncthreads();

    int wv = t >> 6, lane = t & 63;
    int g = lane >> 4;                       // k-subgroup / D row group
    int lr = lane & 15;                      // A row / B col / D col
    int rowbase = blk * 128 + wv * 32;
    int r0 = rowbase + lr, r1 = r0 + 16;
    int rc0 = min(r0, M - 1), rc1 = min(r1, M - 1);

    f32x4 acc[2][8];
    #pragma unroll
    for (int rt = 0; rt < 2; ++rt)
        #pragma unroll
        for (int ct = 0; ct < 8; ++ct)
            acc[rt][ct] = (f32x4)0.0f;

    #pragma unroll
    for (int ks = 0; ks < 4; ++ks) {
        int kof = ks * 32 + g * 8;
        bf16x8 ahi[2], alo[2];
        if (MODE == 0) {
            const float* A = (const float*)Ap;
            #pragma unroll
            for (int rt = 0; rt < 2; ++rt) {
                const float4* p = (const float4*)(A + (size_t)(rt ? rc1 : rc0) * 128 + kof);
                float4 u0 = p[0], u1 = p[1];
                float uu[8] = {u0.x, u0.y, u0.z, u0.w, u1.x, u1.y, u1.z, u1.w};
                bf16x8 ah, al;
                #pragma unroll
                for (int q = 0; q < 8; ++q) {
                    ushort hh, ll; splitT(uu[q], hh, ll);
                    ah[q] = (short)hh; al[q] = (short)ll;
                }
                ahi[rt] = ah; alo[rt] = al;
            }
        } else {
            const ushort* A = (const ushort*)Ap;
            ahi[0] = *(const bf16x8*)(A + (size_t)rc0 * 128 + kof);
            ahi[1] = *(const bf16x8*)(A + (size_t)rc1 * 128 + kof);
        }
        #pragma unroll
        for (int ct = 0; ct < 8; ++ct) {
            int n = ct * 16 + lr;
            int I = (n * 128 + kof) ^ ((n & 7) << 3);
            bf16x8 bhi = *(const bf16x8*)&Wt[I];
            bf16x8 blo = *(const bf16x8*)&Wt[I + 16384];
            #pragma unroll
            for (int rt = 0; rt < 2; ++rt) {
                acc[rt][ct] = __builtin_amdgcn_mfma_f32_16x16x32_bf16(ahi[rt], bhi, acc[rt][ct], 0, 0, 0);
                acc[rt][ct] = __builtin_amdgcn_mfma_f32_16x16x32_bf16(ahi[rt], blo, acc[rt][ct], 0, 0, 0);
                if (MODE == 0)
                    acc[rt][ct] = __builtin_amdgcn_mfma_f32_16x16x32_bf16(alo[rt], bhi, acc[rt][ct], 0, 0, 0);
            }
        }
    }

    #pragma unroll
    for (int rt = 0; rt < 2; ++rt) {
        #pragma unroll
        for (int r = 0; r < 4; ++r) {
            int row = rowbase + rt * 16 + g * 4 + r;
            if (row < M) {
                #pragma unroll
                for (int ct = 0; ct < 8; ++ct)
                    out[(size_t)row * 128 + ct * 16 + lr] = f2bfu(acc[rt][ct][r]);
            }
        }
    }
}

template <int MODE>
__global__ __launch_bounds__(256) void gemm_mfma(
    const void* __restrict__ Ap, const ushort* __restrict__ Wsp,
    ushort* __restrict__ out, int M)
{
    __shared__ ushort Wt[2 * 128 * 128];
    gemm_body<MODE>(Wt, Ap, Wsp, out, M, blockIdx.x);
}

// --- K1: gemm1 (blocks < gemmGrid) fused with bucket_count (rest) ----------
__global__ __launch_bounds__(256) void gemm1_count(
    const float* __restrict__ x, const ushort* __restrict__ Wsp,
    ushort* __restrict__ h, int M, int gemmGrid,
    const int* __restrict__ dst, int* __restrict__ bcnt, int E, int nb, int epb)
{
    __shared__ ushort Wt[2 * 128 * 128];
    if ((int)blockIdx.x >= gemmGrid) {
        int* lhist = (int*)Wt;
        int b = blockIdx.x - gemmGrid;
        int t = threadIdx.x;
        int seg = b & (NSEG - 1);
        int e0 = b * epb, e1 = min(E, e0 + epb);
        for (int i = t; i < nb; i += 256) lhist[i] = 0;
        __syncthreads();
        for (int e = e0 + t; e < e1; e += 256) atomicAdd(&lhist[dst[e] >> 7], 1);
        __syncthreads();
        for (int i = t; i < nb; i += 256) {
            int v = lhist[i];
            if (v) atomicAdd(&bcnt[i * NSEG + seg], v);
        }
        return;
    }
    gemm_body<0>(Wt, x, Wsp, h, M, blockIdx.x);
}

// --- Aggregation: 2 nodes/wave (32-lane halves), uint2 gathers, 8-deep -----
#define FMA4(v, wgt) do { float wf_ = (wgt); \
    acc.x += bfl((v).x) * wf_; acc.y += bfh((v).x) * wf_; \
    acc.z += bfl((v).y) * wf_; acc.w += bfh((v).y) * wf_; } while (0)

template <bool RELU, bool OUTBF>
__global__ __launch_bounds__(1024) void agg_kernel(
    const ushort* __restrict__ h, const float* __restrict__ dinv,
    const int* __restrict__ rowptr, const int* __restrict__ csrsrc,
    const float* __restrict__ bias, void* __restrict__ outv, int n)
{
    __shared__ int2 epair[16][64];
    int t = threadIdx.x;
    int wv = t >> 6;
    int lane = t & 63;
    int half = lane >> 5, sub = lane & 31;
    int node = (blockIdx.x * 16 + wv) * 2 + half;
    bool active = node < n;
    int nodeC = active ? node : (n - 1);

    const uint2* h2 = (const uint2*)h;
    float di = dinv[nodeC];
    int beg = rowptr[nodeC];
    int m = rowptr[nodeC + 1] - beg;

    uint2 vs = h2[(size_t)nodeC * 32 + sub];
    float w0 = di * di;
    float4 acc;
    acc.x = bfl(vs.x) * w0; acc.y = bfh(vs.x) * w0;
    acc.z = bfl(vs.y) * w0; acc.w = bfh(vs.y) * w0;

    int mA = __shfl(m, 0), mB = __shfl(m, 32);
    int mmax = max(mA, mB);

    for (int eb = 0; eb < mmax; eb += 32) {
        int sl = 0; float dlw = 0.0f;
        if (active && (eb + sub) < m) {
            sl = csrsrc[beg + eb + sub];
            dlw = di * dinv[sl];
        }
        epair[wv][lane] = make_int2(sl, __float_as_int(dlw));
        int nq = mmax - eb; if (nq > 32) nq = 32;
        const int2* ep = &epair[wv][half * 32];
        for (int j = 0; j < nq; j += 8) {
            int2 p0 = ep[j + 0], p1 = ep[j + 1], p2 = ep[j + 2], p3 = ep[j + 3];
            int2 p4 = ep[j + 4], p5 = ep[j + 5], p6 = ep[j + 6], p7 = ep[j + 7];
            uint2 v0 = h2[(size_t)(uint)p0.x * 32 + sub];
            uint2 v1 = h2[(size_t)(uint)p1.x * 32 + sub];
            uint2 v2 = h2[(size_t)(uint)p2.x * 32 + sub];
            uint2 v3 = h2[(size_t)(uint)p3.x * 32 + sub];
            uint2 v4 = h2[(size_t)(uint)p4.x * 32 + sub];
            uint2 v5 = h2[(size_t)(uint)p5.x * 32 + sub];
            uint2 v6 = h2[(size_t)(uint)p6.x * 32 + sub];
            uint2 v7 = h2[(size_t)(uint)p7.x * 32 + sub];
            FMA4(v0, __int_as_float(p0.y));
            FMA4(v1, __int_as_float(p1.y));
            FMA4(v2, __int_as_float(p2.y));
            FMA4(v3, __int_as_float(p3.y));
            FMA4(v4, __int_as_float(p4.y));
            FMA4(v5, __int_as_float(p5.y));
            FMA4(v6, __int_as_float(p6.y));
            FMA4(v7, __int_as_float(p7.y));
        }
    }

    float4 bb = ((const float4*)bias)[sub];
    acc.x += bb.x; acc.y += bb.y; acc.z += bb.z; acc.w += bb.w;
    if (RELU) {
        acc.x = fmaxf(acc.x, 0.0f); acc.y = fmaxf(acc.y, 0.0f);
        acc.z = fmaxf(acc.z, 0.0f); acc.w = fmaxf(acc.w, 0.0f);
    }
    if (active) {
        if (OUTBF) {
            uint2 o;
            o.x = (uint)f2bfu(acc.x) | ((uint)f2bfu(acc.y) << 16);
            o.y = (uint)f2bfu(acc.z) | ((uint)f2bfu(acc.w) << 16);
            ((uint2*)outv)[(size_t)node * 32 + sub] = o;
        } else {
            ((float4*)outv)[(size_t)node * 32 + sub] = acc;
        }
    }
}

extern "C" void kernel_launch(void* const* d_in, const int* in_sizes, int n_in,
                              void* d_out, int out_size, void* d_ws, size_t ws_size,
                              hipStream_t stream)
{
    const float* x  = (const float*)d_in[0];
    const int*   ei = (const int*)d_in[1];
    const float* W1 = (const float*)d_in[2];
    const float* b1 = (const float*)d_in[3];
    const float* W2 = (const float*)d_in[4];
    const float* b2 = (const float*)d_in[5];

    const int N = in_sizes[0] / 128;
    const int E = in_sizes[1] / 2;
    const int* esrc = ei;         // edge_index[0]
    const int* edst = ei + E;     // edge_index[1]
    const int nb = (N + 127) >> 7;           // 782 buckets

    char* ws = (char*)d_ws;
    size_t off = 0;
    auto alloc = [&](size_t bytes) -> void* {
        void* p = ws + off;
        off += (bytes + 255) & ~(size_t)255;
        return p;
    };
    ushort* h      = (ushort*)alloc((size_t)N * 128 * sizeof(ushort));   // bf16 h
    uint*   ppack  = (uint*)  alloc((size_t)E * sizeof(uint));
    int*    csrsrc = (int*)   alloc((size_t)E * sizeof(int));
    int*    rowptr = (int*)   alloc((size_t)(N + 1) * sizeof(int));
    float*  dinv   = (float*) alloc((size_t)N * sizeof(float));
    int*    bcnt   = (int*)   alloc((size_t)(NSEG * nb) * sizeof(int));
    int*    ptr    = (int*)   alloc((size_t)(NSEG * nb + 1) * sizeof(int));
    int*    cur    = (int*)   alloc((size_t)(NSEG * nb) * sizeof(int));
    ushort* Ws1    = (ushort*)alloc(2 * 128 * 128 * sizeof(ushort));
    ushort* Ws2    = (ushort*)alloc(2 * 128 * 128 * sizeof(ushort));

    const int gridA = 512;
    const int epb = (E + gridA - 1) / gridA;
    const int gemmGrid = (N + 127) / 128;

    // K0: W pre-split + bcnt zero
    wsplit_init<<<128, 256, 0, stream>>>(W1, W2, Ws1, Ws2, bcnt, NSEG * nb);
    // K1: gemm1 (x@W1 -> h bf16) fused with bucket_count
    gemm1_count<<<gemmGrid + gridA, 256, 0, stream>>>(x, Ws1, h, N, gemmGrid,
                                                      edst, bcnt, E, nb, epb);
    // K2-K4: scan, place, finalize
    scan_seg<<<1, 1024, 0, stream>>>(bcnt, ptr, cur, NSEG * nb, E);
    bucket_place<<<gridA, 256, 0, stream>>>(esrc, edst, cur, ppack, E, nb, epb);
    csr_finalize<<<nb, 256, 0, stream>>>(ppack, ptr, rowptr, csrsrc, dinv, N, E);
    // K5: layer-1 aggregate -> d_out (bf16 scratch)
    agg_kernel<true, true><<<(N + 31) / 32, 1024, 0, stream>>>(h, dinv, rowptr, csrsrc,
                                                               b1, d_out, N);
    // K6: gemm2 (d_out@W2 -> h bf16)
    gemm_mfma<1><<<gemmGrid, 256, 0, stream>>>(d_out, Ws2, h, N);
    // K7: layer-2 aggregate -> d_out (fp32 final)
    agg_kernel<false, false><<<(N + 31) / 32, 1024, 0, stream>>>(h, dinv, rowptr, csrsrc,
                                                                 b2, d_out, N);
}